// Round 3
// baseline (340.673 us; speedup 1.0000x reference)
//
#include <hip/hip_runtime.h>
#include <hip/hip_bf16.h>

typedef __attribute__((ext_vector_type(8))) short short8;
typedef __attribute__((ext_vector_type(4))) short short4v;
typedef __attribute__((ext_vector_type(4))) float f32x4;

#define SCALE_Q 0.17677669529663687f

__device__ __forceinline__ short f2bf(float f) {
  union { float f; unsigned u; } v; v.f = f;
  unsigned r = (v.u + 0x7fffu + ((v.u >> 16) & 1u)) >> 16;
  return (short)r;
}

__device__ __forceinline__ short8 pack8(float4 a, float4 b) {
  short8 s;
  s[0] = f2bf(a.x); s[1] = f2bf(a.y); s[2] = f2bf(a.z); s[3] = f2bf(a.w);
  s[4] = f2bf(b.x); s[5] = f2bf(b.y); s[6] = f2bf(b.z); s[7] = f2bf(b.w);
  return s;
}

// ---------------------------------------------------------------------------
// k_prep: (a) combined attention bias table tab[wdx][h][m][n] = mask + rpb
//         (b) qkv_w / proj_w fp32 -> bf16 in ws
// ---------------------------------------------------------------------------
__global__ __launch_bounds__(256) void k_prep(
    const float* __restrict__ mask, const float* __restrict__ rpb,
    const float* __restrict__ qkvw, const float* __restrict__ pw,
    float* __restrict__ tab, short* __restrict__ wbf, short* __restrict__ pwbf)
{
  const int bid = blockIdx.x, tid = threadIdx.x;
  if (bid < 256) {
    const int wdx = bid >> 2, h = bid & 3;
    for (int t = tid; t < 2401; t += 256) {
      unsigned m = (unsigned)t / 49u;
      unsigned n = (unsigned)t - m * 49u;
      int mi = ((int)m * 37) >> 8, mj = (int)m - mi * 7;
      int ni = ((int)n * 37) >> 8, nj = (int)n - ni * 7;
      int ridx = (mi - ni + 6) * 13 + (mj - nj + 6);
      tab[(size_t)bid * 2401 + t] = mask[(size_t)wdx * 2401 + t] + rpb[ridx * 4 + h];
    }
  } else {
    const int j = bid - 256;                   // 0..7
    for (int i = 0; i < 8; ++i) {
      int idx4 = (j * 8 + i) * 256 + tid;      // float4 index
      if (idx4 < 12288) {
        float4 v = *reinterpret_cast<const float4*>(&qkvw[(size_t)idx4 * 4]);
        short4v s; s[0] = f2bf(v.x); s[1] = f2bf(v.y); s[2] = f2bf(v.z); s[3] = f2bf(v.w);
        *reinterpret_cast<short4v*>(&wbf[(size_t)idx4 * 4]) = s;
      } else {
        int r = idx4 - 12288;
        float4 v = *reinterpret_cast<const float4*>(&pw[(size_t)r * 4]);
        short4v s; s[0] = f2bf(v.x); s[1] = f2bf(v.y); s[2] = f2bf(v.z); s[3] = f2bf(v.w);
        *reinterpret_cast<short4v*>(&pwbf[(size_t)r * 4]) = s;
      }
    }
  }
}

// ---------------------------------------------------------------------------
// k_fused: one window per block, 4 waves; wave w owns rows [w*16, w*16+16).
// Per head: qkv MFMA (B-frags from L1/L2) -> q,k,Vt LDS -> sync -> QK^T ->
// +bias table (prefetched) -> softmax -> P LDS (own rows) -> PV -> ao LDS
// (own rows) -> proj accumulate -> sync.  fp32 out written once.
// ---------------------------------------------------------------------------
__global__ __launch_bounds__(256, 4) void k_fused(
    const float* __restrict__ x, const float* __restrict__ qkvb,
    const float* __restrict__ pb, const float* __restrict__ tab,
    const short* __restrict__ wbf, const short* __restrict__ pwbf,
    float* __restrict__ out)
{
  __shared__ short QK[64][152];   // cols: q 0..31 | k 40..71 | P/ao 80..143
  __shared__ short Vt[32][72];    // V transposed: [d][token]
  const int tid = threadIdx.x;
  const int lane = tid & 63;
  const int sub = tid >> 6;            // wave id = row quarter
  const int l15 = lane & 15, grp = lane >> 4;
  const int gwin = blockIdx.x;
  const int wdx = gwin & 63;
  const size_t xbase = (size_t)gwin * 49 * 128;

  // ---- x A-fragments in registers (rows >=49 zero), reused all heads ----
  short8 xf[4];
  {
    int lr = sub * 16 + l15;
    bool valid = lr < 49;
    for (int ks = 0; ks < 4; ++ks) {
      short8 f = (short8){0, 0, 0, 0, 0, 0, 0, 0};
      if (valid) {
        const float* p = &x[xbase + (size_t)lr * 128 + ks * 32 + grp * 8];
        float4 a = *reinterpret_cast<const float4*>(p);
        float4 b = *reinterpret_cast<const float4*>(p + 4);
        f = pack8(a, b);
      }
      xf[ks] = f;
    }
  }

  f32x4 pacc[8];
  for (int nt = 0; nt < 8; ++nt) pacc[nt] = (f32x4){0, 0, 0, 0};

  for (int h = 0; h < 4; ++h) {
    // ---- prefetch softmax bias-table values for own rows (off crit path) ----
    float tbv[4][4];
    for (int r = 0; r < 4; ++r) {
      int m = sub * 16 + grp * 4 + r;
      const float* trow = &tab[((size_t)(wdx * 4 + h) * 49 + (m < 49 ? m : 0)) * 49];
      for (int nt = 0; nt < 4; ++nt) {
        int n = nt * 16 + l15;
        tbv[r][nt] = (n < 49) ? trow[n] : 0.0f;
      }
    }

    // ---- qkv GEMM: own 16 rows x 96 cols (q,k,v of head h), K=128 ----
    f32x4 acc[6];
    for (int nt = 0; nt < 6; ++nt) {
      int brow = (nt >> 1) * 128 + h * 32 + (nt & 1) * 16 + l15;
      float bv = qkvb[brow];
      acc[nt] = (f32x4){bv, bv, bv, bv};
    }
    for (int ks = 0; ks < 4; ++ks) {
      short8 bfr[6];
      for (int nt = 0; nt < 6; ++nt) {
        int brow = (nt >> 1) * 128 + h * 32 + (nt & 1) * 16 + l15;
        bfr[nt] = *reinterpret_cast<const short8*>(&wbf[(size_t)brow * 128 + ks * 32 + grp * 8]);
      }
      for (int nt = 0; nt < 6; ++nt)
        acc[nt] = __builtin_amdgcn_mfma_f32_16x16x32_bf16(xf[ks], bfr[nt], acc[nt], 0, 0, 0);
    }
    // ---- write q (scaled), k, Vt to LDS ----
    for (int r = 0; r < 4; ++r) {
      int lr = sub * 16 + grp * 4 + r;
      QK[lr][l15]      = f2bf(acc[0][r] * SCALE_Q);
      QK[lr][16 + l15] = f2bf(acc[1][r] * SCALE_Q);
      QK[lr][40 + l15] = f2bf(acc[2][r]);
      QK[lr][56 + l15] = f2bf(acc[3][r]);
      Vt[l15][lr]      = f2bf(acc[4][r]);
      Vt[16 + l15][lr] = f2bf(acc[5][r]);
    }
    __syncthreads();

    // ---- QK^T (K=32, own 16 query rows x all 64 keys) ----
    short8 qa = *reinterpret_cast<const short8*>(&QK[sub * 16 + l15][grp * 8]);
    short8 kb[4];
    for (int nt = 0; nt < 4; ++nt)
      kb[nt] = *reinterpret_cast<const short8*>(&QK[nt * 16 + l15][40 + grp * 8]);
    f32x4 att[4];
    for (int nt = 0; nt < 4; ++nt) att[nt] = (f32x4){0, 0, 0, 0};
    for (int nt = 0; nt < 4; ++nt)
      att[nt] = __builtin_amdgcn_mfma_f32_16x16x32_bf16(qa, kb[nt], att[nt], 0, 0, 0);

    // ---- bias + softmax (defer 1/sum); P -> LDS bf16 (own rows) ----
    float rinv[4];
    for (int r = 0; r < 4; ++r) {
      int m = sub * 16 + grp * 4 + r;
      float v[4];
      for (int nt = 0; nt < 4; ++nt) {
        int n = nt * 16 + l15;
        v[nt] = (m < 49 && n < 49) ? att[nt][r] + tbv[r][nt] : -1e30f;
      }
      float mx = fmaxf(fmaxf(v[0], v[1]), fmaxf(v[2], v[3]));
      for (int d = 1; d < 16; d <<= 1) mx = fmaxf(mx, __shfl_xor(mx, d));
      float s = 0.f;
      for (int nt = 0; nt < 4; ++nt) {
        float e = __expf(v[nt] - mx);
        s += e;
        QK[m][80 + nt * 16 + l15] = f2bf(e);
      }
      for (int d = 1; d < 16; d <<= 1) s += __shfl_xor(s, d);
      rinv[r] = 1.0f / s;
    }
    // own rows only -> no barrier before PV

    // ---- PV: (own 16 x 64 keys) @ (64 keys x 32 d) ----
    short8 pa[2], vb[2][2];
    for (int ks = 0; ks < 2; ++ks)
      pa[ks] = *reinterpret_cast<const short8*>(&QK[sub * 16 + l15][80 + ks * 32 + grp * 8]);
    for (int dt = 0; dt < 2; ++dt)
      for (int ks = 0; ks < 2; ++ks)
        vb[dt][ks] = *reinterpret_cast<const short8*>(&Vt[dt * 16 + l15][ks * 32 + grp * 8]);
    f32x4 o[2];
    for (int dt = 0; dt < 2; ++dt) o[dt] = (f32x4){0, 0, 0, 0};
    for (int ks = 0; ks < 2; ++ks)
      for (int dt = 0; dt < 2; ++dt)
        o[dt] = __builtin_amdgcn_mfma_f32_16x16x32_bf16(pa[ks], vb[dt][ks], o[dt], 0, 0, 0);

    // ---- ao (normalized, bf16) -> LDS (reuse P cols 80..111, own rows) ----
    for (int dt = 0; dt < 2; ++dt)
      for (int r = 0; r < 4; ++r) {
        int lr = sub * 16 + grp * 4 + r;
        QK[lr][80 + dt * 16 + l15] = f2bf(o[dt][r] * rinv[r]);
      }

    // ---- proj accumulate: pacc += ao @ pw_h^T (K=32 slice) ----
    short8 aoa = *reinterpret_cast<const short8*>(&QK[sub * 16 + l15][80 + grp * 8]);
    for (int nt = 0; nt < 8; ++nt) {
      short8 pbv = *reinterpret_cast<const short8*>(&pwbf[(size_t)(nt * 16 + l15) * 128 + h * 32 + grp * 8]);
      pacc[nt] = __builtin_amdgcn_mfma_f32_16x16x32_bf16(aoa, pbv, pacc[nt], 0, 0, 0);
    }
    __syncthreads();   // protect q/k/Vt rewrite (next head) vs cross-wave reads
  }

  // ---- epilogue: + proj bias, write fp32 out (B,N,C) ----
  for (int r = 0; r < 4; ++r) {
    int lr = sub * 16 + grp * 4 + r;
    if (lr < 49) {
      float* orow = &out[xbase + (size_t)lr * 128];
      for (int nt = 0; nt < 8; ++nt)
        orow[nt * 16 + l15] = pacc[nt][r] + pb[nt * 16 + l15];
    }
  }
}

// ---------------------------------------------------------------------------
extern "C" void kernel_launch(void* const* d_in, const int* in_sizes, int n_in,
                              void* d_out, int out_size, void* d_ws, size_t ws_size,
                              hipStream_t stream) {
  const float* x    = (const float*)d_in[0];
  const float* mask = (const float*)d_in[1];
  const float* qkvw = (const float*)d_in[2];
  const float* qkvb = (const float*)d_in[3];
  const float* rpb  = (const float*)d_in[4];
  const float* pw   = (const float*)d_in[5];
  const float* pb   = (const float*)d_in[6];
  float* out = (float*)d_out;

  char* ws = (char*)d_ws;
  short* wbf  = (short*)ws;                 // 384*128 bf16 = 98,304 B
  short* pwbf = (short*)(ws + 98304);       // 128*128 bf16 = 32,768 B
  float* tab  = (float*)(ws + 131072);      // 64*4*49*49 fp32 = 2,458,624 B

  k_prep <<<264,  256, 0, stream>>>(mask, rpb, qkvw, pw, tab, wbf, pwbf);
  k_fused<<<4096, 256, 0, stream>>>(x, qkvb, pb, tab, wbf, pwbf, out);
}

// Round 4
// 260.996 us; speedup vs baseline: 1.3053x; 1.3053x over previous
//
#include <hip/hip_runtime.h>
#include <hip/hip_bf16.h>

typedef __attribute__((ext_vector_type(8))) short short8;
typedef __attribute__((ext_vector_type(4))) short short4v;
typedef __attribute__((ext_vector_type(4))) float f32x4;

#define SCALE_Q 0.17677669529663687f

__device__ __forceinline__ short f2bf(float f) {
  union { float f; unsigned u; } v; v.f = f;
  unsigned r = (v.u + 0x7fffu + ((v.u >> 16) & 1u)) >> 16;
  return (short)r;
}

__device__ __forceinline__ short8 pack8(float4 a, float4 b) {
  short8 s;
  s[0] = f2bf(a.x); s[1] = f2bf(a.y); s[2] = f2bf(a.z); s[3] = f2bf(a.w);
  s[4] = f2bf(b.x); s[5] = f2bf(b.y); s[6] = f2bf(b.z); s[7] = f2bf(b.w);
  return s;
}

// ---------------------------------------------------------------------------
// k_prep: (a) combined attention bias table tab[wdx][h][m][n] = mask + rpb
//         (b) qkv_w / proj_w fp32 -> bf16 in ws
// ---------------------------------------------------------------------------
__global__ __launch_bounds__(256) void k_prep(
    const float* __restrict__ mask, const float* __restrict__ rpb,
    const float* __restrict__ qkvw, const float* __restrict__ pw,
    float* __restrict__ tab, short* __restrict__ wbf, short* __restrict__ pwbf)
{
  const int bid = blockIdx.x, tid = threadIdx.x;
  if (bid < 256) {
    const int wdx = bid >> 2, h = bid & 3;
    for (int t = tid; t < 2401; t += 256) {
      unsigned m = (unsigned)t / 49u;
      unsigned n = (unsigned)t - m * 49u;
      int mi = ((int)m * 37) >> 8, mj = (int)m - mi * 7;
      int ni = ((int)n * 37) >> 8, nj = (int)n - ni * 7;
      int ridx = (mi - ni + 6) * 13 + (mj - nj + 6);
      tab[(size_t)bid * 2401 + t] = mask[(size_t)wdx * 2401 + t] + rpb[ridx * 4 + h];
    }
  } else {
    const int j = bid - 256;                   // 0..7
    for (int i = 0; i < 8; ++i) {
      int idx4 = (j * 8 + i) * 256 + tid;      // float4 index
      if (idx4 < 12288) {
        float4 v = *reinterpret_cast<const float4*>(&qkvw[(size_t)idx4 * 4]);
        short4v s; s[0] = f2bf(v.x); s[1] = f2bf(v.y); s[2] = f2bf(v.z); s[3] = f2bf(v.w);
        *reinterpret_cast<short4v*>(&wbf[(size_t)idx4 * 4]) = s;
      } else {
        int r = idx4 - 12288;
        float4 v = *reinterpret_cast<const float4*>(&pw[(size_t)r * 4]);
        short4v s; s[0] = f2bf(v.x); s[1] = f2bf(v.y); s[2] = f2bf(v.z); s[3] = f2bf(v.w);
        *reinterpret_cast<short4v*>(&pwbf[(size_t)r * 4]) = s;
      }
    }
  }
}

// ---------------------------------------------------------------------------
// k_attn: qkv projection + window attention, one window per block, 4 waves;
// wave w owns query rows [w*16, w*16+16). Output ao (bf16, B,N,C layout).
// Proj GEMM is a separate kernel (register-pressure relief: no pacc/pwbf).
// ---------------------------------------------------------------------------
__global__ __launch_bounds__(256, 4) void k_attn(
    const float* __restrict__ x, const float* __restrict__ qkvb,
    const float* __restrict__ tab, const short* __restrict__ wbf,
    short* __restrict__ ao)
{
  __shared__ short QK[64][152];   // cols: q 0..31 | k 40..71 | P 80..143
  __shared__ short Vt[32][72];    // V transposed: [d][token]
  const int tid = threadIdx.x;
  const int lane = tid & 63;
  const int sub = tid >> 6;            // wave id = row quarter
  const int l15 = lane & 15, grp = lane >> 4;
  const int gwin = blockIdx.x;
  const int wdx = gwin & 63;
  const size_t xbase = (size_t)gwin * 49 * 128;

  // ---- x A-fragments in registers (rows >=49 zero), reused all heads ----
  short8 xf[4];
  {
    int lr = sub * 16 + l15;
    bool valid = lr < 49;
    for (int ks = 0; ks < 4; ++ks) {
      short8 f = (short8){0, 0, 0, 0, 0, 0, 0, 0};
      if (valid) {
        const float* p = &x[xbase + (size_t)lr * 128 + ks * 32 + grp * 8];
        float4 a = *reinterpret_cast<const float4*>(p);
        float4 b = *reinterpret_cast<const float4*>(p + 4);
        f = pack8(a, b);
      }
      xf[ks] = f;
    }
  }

  for (int h = 0; h < 4; ++h) {
    // ---- qkv GEMM: own 16 rows x 96 cols (q,k,v of head h), K=128 ----
    f32x4 acc[6];
    for (int nt = 0; nt < 6; ++nt) {
      int brow = (nt >> 1) * 128 + h * 32 + (nt & 1) * 16 + l15;
      float bv = qkvb[brow];
      acc[nt] = (f32x4){bv, bv, bv, bv};
    }
    for (int ks = 0; ks < 4; ++ks) {
      short8 bfr[6];
      for (int nt = 0; nt < 6; ++nt) {
        int brow = (nt >> 1) * 128 + h * 32 + (nt & 1) * 16 + l15;
        bfr[nt] = *reinterpret_cast<const short8*>(&wbf[(size_t)brow * 128 + ks * 32 + grp * 8]);
      }
      for (int nt = 0; nt < 6; ++nt)
        acc[nt] = __builtin_amdgcn_mfma_f32_16x16x32_bf16(xf[ks], bfr[nt], acc[nt], 0, 0, 0);
    }
    // ---- write q (scaled), k, Vt to LDS ----
    for (int r = 0; r < 4; ++r) {
      int lr = sub * 16 + grp * 4 + r;
      QK[lr][l15]      = f2bf(acc[0][r] * SCALE_Q);
      QK[lr][16 + l15] = f2bf(acc[1][r] * SCALE_Q);
      QK[lr][40 + l15] = f2bf(acc[2][r]);
      QK[lr][56 + l15] = f2bf(acc[3][r]);
      Vt[l15][lr]      = f2bf(acc[4][r]);
      Vt[16 + l15][lr] = f2bf(acc[5][r]);
    }
    // ---- prefetch softmax bias-table rows (hides L2 latency past barrier) --
    float tbv[4][4];
    for (int r = 0; r < 4; ++r) {
      int m = sub * 16 + grp * 4 + r;
      const float* trow = &tab[((size_t)(wdx * 4 + h) * 49 + (m < 49 ? m : 0)) * 49];
      for (int nt = 0; nt < 4; ++nt) {
        int n = nt * 16 + l15;
        tbv[r][nt] = (n < 49) ? trow[n] : 0.0f;
      }
    }
    __syncthreads();

    // ---- QK^T (K=32, own 16 query rows x all 64 keys) ----
    short8 qa = *reinterpret_cast<const short8*>(&QK[sub * 16 + l15][grp * 8]);
    short8 kb[4];
    for (int nt = 0; nt < 4; ++nt)
      kb[nt] = *reinterpret_cast<const short8*>(&QK[nt * 16 + l15][40 + grp * 8]);
    f32x4 att[4];
    for (int nt = 0; nt < 4; ++nt) att[nt] = (f32x4){0, 0, 0, 0};
    for (int nt = 0; nt < 4; ++nt)
      att[nt] = __builtin_amdgcn_mfma_f32_16x16x32_bf16(qa, kb[nt], att[nt], 0, 0, 0);

    // ---- bias + softmax (defer 1/sum); P -> LDS bf16 (own rows) ----
    float rinv[4];
    for (int r = 0; r < 4; ++r) {
      int m = sub * 16 + grp * 4 + r;
      float v[4];
      for (int nt = 0; nt < 4; ++nt) {
        int n = nt * 16 + l15;
        v[nt] = (m < 49 && n < 49) ? att[nt][r] + tbv[r][nt] : -1e30f;
      }
      float mx = fmaxf(fmaxf(v[0], v[1]), fmaxf(v[2], v[3]));
      for (int d = 1; d < 16; d <<= 1) mx = fmaxf(mx, __shfl_xor(mx, d));
      float s = 0.f;
      for (int nt = 0; nt < 4; ++nt) {
        float e = __expf(v[nt] - mx);
        s += e;
        QK[m][80 + nt * 16 + l15] = f2bf(e);
      }
      for (int d = 1; d < 16; d <<= 1) s += __shfl_xor(s, d);
      rinv[r] = 1.0f / s;
    }
    // own rows only -> no barrier before PV

    // ---- PV: (own 16 x 64 keys) @ (64 keys x 32 d) ----
    short8 pa[2], vb[2][2];
    for (int ks = 0; ks < 2; ++ks)
      pa[ks] = *reinterpret_cast<const short8*>(&QK[sub * 16 + l15][80 + ks * 32 + grp * 8]);
    for (int dt = 0; dt < 2; ++dt)
      for (int ks = 0; ks < 2; ++ks)
        vb[dt][ks] = *reinterpret_cast<const short8*>(&Vt[dt * 16 + l15][ks * 32 + grp * 8]);
    f32x4 o[2];
    for (int dt = 0; dt < 2; ++dt) o[dt] = (f32x4){0, 0, 0, 0};
    for (int ks = 0; ks < 2; ++ks)
      for (int dt = 0; dt < 2; ++dt)
        o[dt] = __builtin_amdgcn_mfma_f32_16x16x32_bf16(pa[ks], vb[dt][ks], o[dt], 0, 0, 0);

    // ---- ao (normalized, bf16) -> global (B,N,C); L2 merges 32B pairs ----
    for (int r = 0; r < 4; ++r) {
      int lr = sub * 16 + grp * 4 + r;
      if (lr < 49) {
        size_t base = (xbase + (size_t)lr * 128 + h * 32);
        for (int dt = 0; dt < 2; ++dt)
          ao[base + dt * 16 + l15] = f2bf(o[dt][r] * rinv[r]);
      }
    }
    __syncthreads();   // protect q/k/Vt rewrite (next head) vs cross-wave reads
  }
}

// ---------------------------------------------------------------------------
// k_proj: out = ao @ pw^T + pb  (M=200704, N=128, K=128), fp32 out.
// Zero LDS: A-frags direct from global (one-touch), B-frags from L2 pwbf.
// Block = 64 rows, 4 waves = 2(M) x 2(N); wave: 32 rows x 64 cols.
// ---------------------------------------------------------------------------
__global__ __launch_bounds__(256, 4) void k_proj(
    const short* __restrict__ a, const short* __restrict__ pwbf,
    const float* __restrict__ pb, float* __restrict__ out)
{
  const int tid = threadIdx.x;
  const int lane = tid & 63;
  const int wave = tid >> 6;
  const int l15 = lane & 15, grp = lane >> 4;
  const int wm = (wave >> 1), wn = wave & 1;
  const int row0 = blockIdx.x * 64;

  f32x4 acc[2][4];
  for (int mt = 0; mt < 2; ++mt)
    for (int nt = 0; nt < 4; ++nt) acc[mt][nt] = (f32x4){0, 0, 0, 0};

  for (int ks = 0; ks < 4; ++ks) {
    short8 af[2], bfr[4];
    for (int mt = 0; mt < 2; ++mt) {
      int row = row0 + wm * 32 + mt * 16 + l15;
      af[mt] = *reinterpret_cast<const short8*>(&a[(size_t)row * 128 + ks * 32 + grp * 8]);
    }
    for (int nt = 0; nt < 4; ++nt) {
      int col = wn * 64 + nt * 16 + l15;
      bfr[nt] = *reinterpret_cast<const short8*>(&pwbf[(size_t)col * 128 + ks * 32 + grp * 8]);
    }
    for (int mt = 0; mt < 2; ++mt)
      for (int nt = 0; nt < 4; ++nt)
        acc[mt][nt] = __builtin_amdgcn_mfma_f32_16x16x32_bf16(af[mt], bfr[nt], acc[mt][nt], 0, 0, 0);
  }

  for (int mt = 0; mt < 2; ++mt)
    for (int r = 0; r < 4; ++r) {
      size_t row = (size_t)(row0 + wm * 32 + mt * 16 + grp * 4 + r);
      for (int nt = 0; nt < 4; ++nt) {
        int col = wn * 64 + nt * 16 + l15;
        out[row * 128 + col] = acc[mt][nt][r] + pb[col];
      }
    }
}

// ---------------------------------------------------------------------------
extern "C" void kernel_launch(void* const* d_in, const int* in_sizes, int n_in,
                              void* d_out, int out_size, void* d_ws, size_t ws_size,
                              hipStream_t stream) {
  const float* x    = (const float*)d_in[0];
  const float* mask = (const float*)d_in[1];
  const float* qkvw = (const float*)d_in[2];
  const float* qkvb = (const float*)d_in[3];
  const float* rpb  = (const float*)d_in[4];
  const float* pw   = (const float*)d_in[5];
  const float* pb   = (const float*)d_in[6];
  float* out = (float*)d_out;

  char* ws = (char*)d_ws;
  short* wbf  = (short*)ws;                  // 384*128 bf16 = 98,304 B
  short* pwbf = (short*)(ws + 98304);        // 128*128 bf16 = 32,768 B
  float* tab  = (float*)(ws + 131072);       // 64*4*49*49 fp32 = 2,458,624 B
  short* ao   = (short*)(ws + 2589696);      // 200704*128 bf16 = 51,380,224 B

  k_prep<<<264,  256, 0, stream>>>(mask, rpb, qkvw, pw, tab, wbf, pwbf);
  k_attn<<<4096, 256, 0, stream>>>(x, qkvb, tab, wbf, ao);
  k_proj<<<3136, 256, 0, stream>>>(ao, pwbf, pb, out);
}

// Round 5
// 199.394 us; speedup vs baseline: 1.7085x; 1.3089x over previous
//
#include <hip/hip_runtime.h>
#include <hip/hip_bf16.h>

typedef __attribute__((ext_vector_type(8))) short short8;
typedef __attribute__((ext_vector_type(4))) short short4v;
typedef __attribute__((ext_vector_type(4))) float f32x4;

#define SCALE_Q 0.17677669529663687f

__device__ __forceinline__ short f2bf(float f) {
  union { float f; unsigned u; } v; v.f = f;
  unsigned r = (v.u + 0x7fffu + ((v.u >> 16) & 1u)) >> 16;
  return (short)r;
}

union S8U { short8 v; __hip_bfloat162 h[4]; int2 d[2]; };
union W4U { int2 d; __hip_bfloat162 h[2]; };

__device__ __forceinline__ short8 pack8i(float4 a, float4 b) {
  S8U r;
  r.h[0] = __float22bfloat162_rn(make_float2(a.x, a.y));
  r.h[1] = __float22bfloat162_rn(make_float2(a.z, a.w));
  r.h[2] = __float22bfloat162_rn(make_float2(b.x, b.y));
  r.h[3] = __float22bfloat162_rn(make_float2(b.z, b.w));
  return r.v;
}

__device__ __forceinline__ int2 pack4i(float a, float b, float c, float d) {
  W4U w;
  w.h[0] = __float22bfloat162_rn(make_float2(a, b));
  w.h[1] = __float22bfloat162_rn(make_float2(c, d));
  return w.d;
}

// ---------------------------------------------------------------------------
// k_prep: (a) padded bias table tab[wdx][h][64][64]: mask+rpb, -1e30 for n>=49
//             (kills padded keys), 0 for m>=49 rows (never stored).
//         (b) qkv_w / proj_w fp32 -> bf16 in ws
// ---------------------------------------------------------------------------
__global__ __launch_bounds__(256) void k_prep(
    const float* __restrict__ mask, const float* __restrict__ rpb,
    const float* __restrict__ qkvw, const float* __restrict__ pw,
    float* __restrict__ tab, short* __restrict__ wbf, short* __restrict__ pwbf)
{
  const int bid = blockIdx.x, tid = threadIdx.x;
  if (bid < 256) {
    const int wdx = bid >> 2, h = bid & 3;
    for (int t = tid; t < 4096; t += 256) {
      int m = t >> 6, n = t & 63;
      float val;
      if (n >= 49)      val = -1e30f;
      else if (m >= 49) val = 0.0f;
      else {
        int mi = (m * 37) >> 8, mj = m - mi * 7;
        int ni = (n * 37) >> 8, nj = n - ni * 7;
        int ridx = (mi - ni + 6) * 13 + (mj - nj + 6);
        val = mask[(size_t)wdx * 2401 + m * 49 + n] + rpb[ridx * 4 + h];
      }
      tab[(size_t)bid * 4096 + t] = val;
    }
  } else {
    const int j = bid - 256;                   // 0..7
    for (int i = 0; i < 8; ++i) {
      int idx4 = (j * 8 + i) * 256 + tid;      // float4 index
      if (idx4 < 12288) {
        float4 v = *reinterpret_cast<const float4*>(&qkvw[(size_t)idx4 * 4]);
        short4v s; s[0] = f2bf(v.x); s[1] = f2bf(v.y); s[2] = f2bf(v.z); s[3] = f2bf(v.w);
        *reinterpret_cast<short4v*>(&wbf[(size_t)idx4 * 4]) = s;
      } else {
        int r = idx4 - 12288;
        float4 v = *reinterpret_cast<const float4*>(&pw[(size_t)r * 4]);
        short4v s; s[0] = f2bf(v.x); s[1] = f2bf(v.y); s[2] = f2bf(v.z); s[3] = f2bf(v.w);
        *reinterpret_cast<short4v*>(&pwbf[(size_t)r * 4]) = s;
      }
    }
  }
}

// ---------------------------------------------------------------------------
// k_attn: one WAVE per (window, head). 4 waves/block = the 4 heads of window
// blockIdx.x. ZERO barriers: each wave owns a private LDS arena and runs the
// full pipeline: qkv GEMM (64 rows) -> q,k LDS -> swapped QK^T (S^T in regs)
// -> column-softmax (2 shuffles) -> normalized P (b64-packed) -> PV -> ao.
// Arena (shorts, 6656/wave): q[64][32]@0, k[64][32]@2048,
//   P[64][68]@0 (overlays dead q/k), Vt[32][72]@4352.
// ---------------------------------------------------------------------------
__global__ __launch_bounds__(256, 3) void k_attn(
    const float* __restrict__ x, const float* __restrict__ qkvb,
    const float* __restrict__ tab, const short* __restrict__ wbf,
    short* __restrict__ ao)
{
  __shared__ short arena[4][6656];
  const int lane = threadIdx.x & 63;
  const int h = threadIdx.x >> 6;        // wave id = head
  const int l15 = lane & 15, grp = lane >> 4;
  const int gwin = blockIdx.x;
  const int wdx = gwin & 63;
  const size_t xbase = (size_t)gwin * 49 * 128;
  short* const q_lds  = &arena[h][0];      // [64][32]
  short* const k_lds  = &arena[h][2048];   // [64][32]
  short* const P_lds  = &arena[h][0];      // [64][68] overlay
  short* const Vt_lds = &arena[h][4352];   // [32][72]

  // ---- x A-fragments for all 64 rows (rows >=49 zero) ----
  short8 xf[4][4];
  #pragma unroll
  for (int mt = 0; mt < 4; ++mt) {
    int lr = mt * 16 + l15;
    bool valid = lr < 49;
    #pragma unroll
    for (int ks = 0; ks < 4; ++ks) {
      short8 f = (short8){0, 0, 0, 0, 0, 0, 0, 0};
      if (valid) {
        const float* p = &x[xbase + (size_t)lr * 128 + ks * 32 + grp * 8];
        f = pack8i(*reinterpret_cast<const float4*>(p),
                   *reinterpret_cast<const float4*>(p + 4));
      }
      xf[mt][ks] = f;
    }
  }

  // ---- Q,K gemm: 64 rows x 64 cols (q0,q1,k0,k1), K=128 ----
  f32x4 acc[4][4];
  #pragma unroll
  for (int nt = 0; nt < 4; ++nt) {
    int brow = (nt >> 1) * 128 + h * 32 + (nt & 1) * 16 + l15;
    float bv = qkvb[brow];
    #pragma unroll
    for (int mt = 0; mt < 4; ++mt) acc[mt][nt] = (f32x4){bv, bv, bv, bv};
  }
  #pragma unroll
  for (int ks = 0; ks < 4; ++ks) {
    short8 bfr[4];
    #pragma unroll
    for (int nt = 0; nt < 4; ++nt) {
      int brow = (nt >> 1) * 128 + h * 32 + (nt & 1) * 16 + l15;
      bfr[nt] = *reinterpret_cast<const short8*>(&wbf[(size_t)brow * 128 + ks * 32 + grp * 8]);
    }
    #pragma unroll
    for (int mt = 0; mt < 4; ++mt)
      #pragma unroll
      for (int nt = 0; nt < 4; ++nt)
        acc[mt][nt] = __builtin_amdgcn_mfma_f32_16x16x32_bf16(xf[mt][ks], bfr[nt], acc[mt][nt], 0, 0, 0);
  }
  // write q (scaled incl bias) and k rows to LDS [m][d], stride 32
  #pragma unroll
  for (int mt = 0; mt < 4; ++mt)
    #pragma unroll
    for (int r = 0; r < 4; ++r) {
      int m = mt * 16 + grp * 4 + r;
      q_lds[m * 32 + l15]      = f2bf(acc[mt][0][r] * SCALE_Q);
      q_lds[m * 32 + 16 + l15] = f2bf(acc[mt][1][r] * SCALE_Q);
      k_lds[m * 32 + l15]      = f2bf(acc[mt][2][r]);
      k_lds[m * 32 + 16 + l15] = f2bf(acc[mt][3][r]);
    }

  // ---- V gemm: kept in registers until after softmax ----
  f32x4 vacc[4][2];
  #pragma unroll
  for (int dt = 0; dt < 2; ++dt) {
    float bv = qkvb[256 + h * 32 + dt * 16 + l15];
    #pragma unroll
    for (int mt = 0; mt < 4; ++mt) vacc[mt][dt] = (f32x4){bv, bv, bv, bv};
  }
  #pragma unroll
  for (int ks = 0; ks < 4; ++ks) {
    short8 bfr2[2];
    #pragma unroll
    for (int dt = 0; dt < 2; ++dt) {
      int brow = 256 + h * 32 + dt * 16 + l15;
      bfr2[dt] = *reinterpret_cast<const short8*>(&wbf[(size_t)brow * 128 + ks * 32 + grp * 8]);
    }
    #pragma unroll
    for (int mt = 0; mt < 4; ++mt)
      #pragma unroll
      for (int dt = 0; dt < 2; ++dt)
        vacc[mt][dt] = __builtin_amdgcn_mfma_f32_16x16x32_bf16(xf[mt][ks], bfr2[dt], vacc[mt][dt], 0, 0, 0);
  }

  // ---- swapped QK^T: att[nt][mt] = S^T tile, lane holds col m0=mt*16+l15 ----
  short8 kfr[4], qfr[4];
  #pragma unroll
  for (int t = 0; t < 4; ++t) {
    kfr[t] = *reinterpret_cast<const short8*>(&k_lds[(t * 16 + l15) * 32 + grp * 8]);
    qfr[t] = *reinterpret_cast<const short8*>(&q_lds[(t * 16 + l15) * 32 + grp * 8]);
  }
  f32x4 att[4][4];
  #pragma unroll
  for (int nt = 0; nt < 4; ++nt)
    #pragma unroll
    for (int mt = 0; mt < 4; ++mt) att[nt][mt] = (f32x4){0, 0, 0, 0};
  #pragma unroll
  for (int nt = 0; nt < 4; ++nt)
    #pragma unroll
    for (int mt = 0; mt < 4; ++mt)
      att[nt][mt] = __builtin_amdgcn_mfma_f32_16x16x32_bf16(kfr[nt], qfr[mt], att[nt][mt], 0, 0, 0);

  // ---- column softmax: 16 in-reg values + shfl_xor(16,32); P b64-packed ----
  #pragma unroll
  for (int mt = 0; mt < 4; ++mt) {
    const int m0 = mt * 16 + l15;
    const float* trow = &tab[(((size_t)(wdx * 4 + h)) * 64 + m0) * 64];
    float4 tb[4];
    #pragma unroll
    for (int nt = 0; nt < 4; ++nt)
      tb[nt] = *reinterpret_cast<const float4*>(&trow[nt * 16 + grp * 4]);
    float v[4][4];
    #pragma unroll
    for (int nt = 0; nt < 4; ++nt) {
      v[nt][0] = att[nt][mt][0] + tb[nt].x;
      v[nt][1] = att[nt][mt][1] + tb[nt].y;
      v[nt][2] = att[nt][mt][2] + tb[nt].z;
      v[nt][3] = att[nt][mt][3] + tb[nt].w;
    }
    float mx = v[0][0];
    #pragma unroll
    for (int nt = 0; nt < 4; ++nt)
      #pragma unroll
      for (int r = 0; r < 4; ++r) mx = fmaxf(mx, v[nt][r]);
    mx = fmaxf(mx, __shfl_xor(mx, 16));
    mx = fmaxf(mx, __shfl_xor(mx, 32));
    float s = 0.f;
    float p[4][4];
    #pragma unroll
    for (int nt = 0; nt < 4; ++nt)
      #pragma unroll
      for (int r = 0; r < 4; ++r) { p[nt][r] = __expf(v[nt][r] - mx); s += p[nt][r]; }
    s += __shfl_xor(s, 16);
    s += __shfl_xor(s, 32);
    float ri = 1.0f / s;
    #pragma unroll
    for (int nt = 0; nt < 4; ++nt)
      *reinterpret_cast<int2*>(&P_lds[m0 * 68 + nt * 16 + grp * 4]) =
          pack4i(p[nt][0] * ri, p[nt][1] * ri, p[nt][2] * ri, p[nt][3] * ri);
  }

  // ---- Vt from registers -> LDS [d][token], b64-packed (tokens contiguous) --
  #pragma unroll
  for (int dt = 0; dt < 2; ++dt)
    #pragma unroll
    for (int mt = 0; mt < 4; ++mt)
      *reinterpret_cast<int2*>(&Vt_lds[(dt * 16 + l15) * 72 + mt * 16 + grp * 4]) =
          pack4i(vacc[mt][dt][0], vacc[mt][dt][1], vacc[mt][dt][2], vacc[mt][dt][3]);

  // ---- PV: (64 x 64keys) @ (64keys x 32d); P rows via 2x b64 (8B-aligned) --
  short8 pa[4][2], vb[2][2];
  #pragma unroll
  for (int mt = 0; mt < 4; ++mt)
    #pragma unroll
    for (int k2 = 0; k2 < 2; ++k2) {
      S8U t;
      t.d[0] = *reinterpret_cast<const int2*>(&P_lds[(mt * 16 + l15) * 68 + k2 * 32 + grp * 8]);
      t.d[1] = *reinterpret_cast<const int2*>(&P_lds[(mt * 16 + l15) * 68 + k2 * 32 + grp * 8 + 4]);
      pa[mt][k2] = t.v;
    }
  #pragma unroll
  for (int dt = 0; dt < 2; ++dt)
    #pragma unroll
    for (int k2 = 0; k2 < 2; ++k2)
      vb[dt][k2] = *reinterpret_cast<const short8*>(&Vt_lds[(dt * 16 + l15) * 72 + k2 * 32 + grp * 8]);
  f32x4 o[4][2];
  #pragma unroll
  for (int mt = 0; mt < 4; ++mt)
    #pragma unroll
    for (int dt = 0; dt < 2; ++dt) o[mt][dt] = (f32x4){0, 0, 0, 0};
  #pragma unroll
  for (int k2 = 0; k2 < 2; ++k2)
    #pragma unroll
    for (int mt = 0; mt < 4; ++mt)
      #pragma unroll
      for (int dt = 0; dt < 2; ++dt)
        o[mt][dt] = __builtin_amdgcn_mfma_f32_16x16x32_bf16(pa[mt][k2], vb[dt][k2], o[mt][dt], 0, 0, 0);

  // ---- store ao (bf16, B,N,C); P pre-normalized so no rinv here ----
  #pragma unroll
  for (int mt = 0; mt < 4; ++mt)
    #pragma unroll
    for (int r = 0; r < 4; ++r) {
      int m = mt * 16 + grp * 4 + r;
      if (m < 49) {
        size_t base = xbase + (size_t)m * 128 + h * 32;
        #pragma unroll
        for (int dt = 0; dt < 2; ++dt)
          ao[base + dt * 16 + l15] = f2bf(o[mt][dt][r]);
      }
    }
}

// ---------------------------------------------------------------------------
// k_proj: out = ao @ pw^T + pb  (M=200704, N=128, K=128), fp32 out.
// Zero LDS: A-frags direct from global (one-touch), B-frags from L2 pwbf.
// ---------------------------------------------------------------------------
__global__ __launch_bounds__(256, 4) void k_proj(
    const short* __restrict__ a, const short* __restrict__ pwbf,
    const float* __restrict__ pb, float* __restrict__ out)
{
  const int tid = threadIdx.x;
  const int lane = tid & 63;
  const int wave = tid >> 6;
  const int l15 = lane & 15, grp = lane >> 4;
  const int wm = (wave >> 1), wn = wave & 1;
  const int row0 = blockIdx.x * 64;

  f32x4 acc[2][4];
  #pragma unroll
  for (int mt = 0; mt < 2; ++mt)
    #pragma unroll
    for (int nt = 0; nt < 4; ++nt) acc[mt][nt] = (f32x4){0, 0, 0, 0};

  #pragma unroll
  for (int ks = 0; ks < 4; ++ks) {
    short8 af[2], bfr[4];
    #pragma unroll
    for (int mt = 0; mt < 2; ++mt) {
      int row = row0 + wm * 32 + mt * 16 + l15;
      af[mt] = *reinterpret_cast<const short8*>(&a[(size_t)row * 128 + ks * 32 + grp * 8]);
    }
    #pragma unroll
    for (int nt = 0; nt < 4; ++nt) {
      int col = wn * 64 + nt * 16 + l15;
      bfr[nt] = *reinterpret_cast<const short8*>(&pwbf[(size_t)col * 128 + ks * 32 + grp * 8]);
    }
    #pragma unroll
    for (int mt = 0; mt < 2; ++mt)
      #pragma unroll
      for (int nt = 0; nt < 4; ++nt)
        acc[mt][nt] = __builtin_amdgcn_mfma_f32_16x16x32_bf16(af[mt], bfr[nt], acc[mt][nt], 0, 0, 0);
  }

  #pragma unroll
  for (int mt = 0; mt < 2; ++mt)
    #pragma unroll
    for (int r = 0; r < 4; ++r) {
      size_t row = (size_t)(row0 + wm * 32 + mt * 16 + grp * 4 + r);
      #pragma unroll
      for (int nt = 0; nt < 4; ++nt) {
        int col = wn * 64 + nt * 16 + l15;
        out[row * 128 + col] = acc[mt][nt][r] + pb[col];
      }
    }
}

// ---------------------------------------------------------------------------
extern "C" void kernel_launch(void* const* d_in, const int* in_sizes, int n_in,
                              void* d_out, int out_size, void* d_ws, size_t ws_size,
                              hipStream_t stream) {
  const float* x    = (const float*)d_in[0];
  const float* mask = (const float*)d_in[1];
  const float* qkvw = (const float*)d_in[2];
  const float* qkvb = (const float*)d_in[3];
  const float* rpb  = (const float*)d_in[4];
  const float* pw   = (const float*)d_in[5];
  const float* pb   = (const float*)d_in[6];
  float* out = (float*)d_out;

  char* ws = (char*)d_ws;
  short* wbf  = (short*)ws;                  // 384*128 bf16 = 98,304 B
  short* pwbf = (short*)(ws + 98304);        // 128*128 bf16 = 32,768 B
  float* tab  = (float*)(ws + 131072);       // 256*64*64 fp32 = 4,194,304 B
  short* ao   = (short*)(ws + 4325376);      // 200704*128 bf16 = 51,380,224 B

  k_prep<<<264,  256, 0, stream>>>(mask, rpb, qkvw, pw, tab, wbf, pwbf);
  k_attn<<<4096, 256, 0, stream>>>(x, qkvb, tab, wbf, ao);
  k_proj<<<3136, 256, 0, stream>>>(ao, pwbf, pb, out);
}

// Round 6
// 196.970 us; speedup vs baseline: 1.7296x; 1.0123x over previous
//
#include <hip/hip_runtime.h>
#include <hip/hip_bf16.h>

typedef __attribute__((ext_vector_type(8))) short short8;
typedef __attribute__((ext_vector_type(4))) short short4v;
typedef __attribute__((ext_vector_type(4))) float f32x4;

#define SCALE_Q 0.17677669529663687f

__device__ __forceinline__ short f2bf(float f) {
  union { float f; unsigned u; } v; v.f = f;
  unsigned r = (v.u + 0x7fffu + ((v.u >> 16) & 1u)) >> 16;
  return (short)r;
}

union S8U { short8 v; __hip_bfloat162 h[4]; int2 d[2]; };
union W4U { int2 d; __hip_bfloat162 h[2]; };

__device__ __forceinline__ short8 pack8i(float4 a, float4 b) {
  S8U r;
  r.h[0] = __float22bfloat162_rn(make_float2(a.x, a.y));
  r.h[1] = __float22bfloat162_rn(make_float2(a.z, a.w));
  r.h[2] = __float22bfloat162_rn(make_float2(b.x, b.y));
  r.h[3] = __float22bfloat162_rn(make_float2(b.z, b.w));
  return r.v;
}

__device__ __forceinline__ short8 pack8f(f32x4 a, f32x4 b) {
  S8U r;
  r.h[0] = __float22bfloat162_rn(make_float2(a[0], a[1]));
  r.h[1] = __float22bfloat162_rn(make_float2(a[2], a[3]));
  r.h[2] = __float22bfloat162_rn(make_float2(b[0], b[1]));
  r.h[3] = __float22bfloat162_rn(make_float2(b[2], b[3]));
  return r.v;
}

__device__ __forceinline__ int2 pack4i(float a, float b, float c, float d) {
  W4U w;
  w.h[0] = __float22bfloat162_rn(make_float2(a, b));
  w.h[1] = __float22bfloat162_rn(make_float2(c, d));
  return w.d;
}

// ---------------------------------------------------------------------------
// k_prep: (a) padded bias table tab[wdx][h][64][64]: mask+rpb, -1e30 for n>=49
//         (b) qkv_w / proj_w fp32 -> bf16 in ws
// ---------------------------------------------------------------------------
__global__ __launch_bounds__(256) void k_prep(
    const float* __restrict__ mask, const float* __restrict__ rpb,
    const float* __restrict__ qkvw, const float* __restrict__ pw,
    float* __restrict__ tab, short* __restrict__ wbf, short* __restrict__ pwbf)
{
  const int bid = blockIdx.x, tid = threadIdx.x;
  if (bid < 256) {
    const int wdx = bid >> 2, h = bid & 3;
    for (int t = tid; t < 4096; t += 256) {
      int m = t >> 6, n = t & 63;
      float val;
      if (n >= 49)      val = -1e30f;
      else if (m >= 49) val = 0.0f;
      else {
        int mi = (m * 37) >> 8, mj = m - mi * 7;
        int ni = (n * 37) >> 8, nj = n - ni * 7;
        int ridx = (mi - ni + 6) * 13 + (mj - nj + 6);
        val = mask[(size_t)wdx * 2401 + m * 49 + n] + rpb[ridx * 4 + h];
      }
      tab[(size_t)bid * 4096 + t] = val;
    }
  } else {
    const int j = bid - 256;                   // 0..7
    for (int i = 0; i < 8; ++i) {
      int idx4 = (j * 8 + i) * 256 + tid;      // float4 index
      if (idx4 < 12288) {
        float4 v = *reinterpret_cast<const float4*>(&qkvw[(size_t)idx4 * 4]);
        short4v s; s[0] = f2bf(v.x); s[1] = f2bf(v.y); s[2] = f2bf(v.z); s[3] = f2bf(v.w);
        *reinterpret_cast<short4v*>(&wbf[(size_t)idx4 * 4]) = s;
      } else {
        int r = idx4 - 12288;
        float4 v = *reinterpret_cast<const float4*>(&pw[(size_t)r * 4]);
        short4v s; s[0] = f2bf(v.x); s[1] = f2bf(v.y); s[2] = f2bf(v.z); s[3] = f2bf(v.w);
        *reinterpret_cast<short4v*>(&pwbf[(size_t)r * 4]) = s;
      }
    }
  }
}

// ---------------------------------------------------------------------------
// k_fused: one WAVE per (window, head); 4 waves/block = heads of one window.
// All-register attention via k-permutation cancellation:
//   - Q,K gemm SWAPPED (mfma(w,x)) -> lane = token, regs = head-dims.
//   - S^T = mfma(Kpack, Qpack) with matching nonstandard d-order.
//   - PV  = mfma(Vpack, Ppack) with matching nonstandard n-order; V from
//     normal-orientation gemm (lane = d), P from S^T softmax (lane = m).
// Single barrier: heads exchange 32-dim ao slices through LDS, then each
// wave does the proj GEMM for 16 token rows and writes fp32 out.
// ---------------------------------------------------------------------------
__global__ __launch_bounds__(256, 3) void k_fused(
    const float* __restrict__ x, const float* __restrict__ qkvb,
    const float* __restrict__ pb, const float* __restrict__ tab,
    const short* __restrict__ wbf, const short* __restrict__ pwbf,
    float* __restrict__ out)
{
  __shared__ short ao_lds[64][136];     // [token][C]; 272B row = 17x16B
  const int lane = threadIdx.x & 63;
  const int h = threadIdx.x >> 6;       // wave id = head
  const int l15 = lane & 15, grp = lane >> 4;
  const int gwin = blockIdx.x;
  const int wdx = gwin & 63;
  const size_t xbase = (size_t)gwin * 49 * 128;

  // ---- x fragments: lane = token (rows >=49 zero), k = channels grp*8.. ----
  short8 xf[4][4];
  #pragma unroll
  for (int tt = 0; tt < 4; ++tt) {
    int lr = tt * 16 + l15;
    bool valid = lr < 49;
    #pragma unroll
    for (int ks = 0; ks < 4; ++ks) {
      short8 f = (short8){0, 0, 0, 0, 0, 0, 0, 0};
      if (valid) {
        const float* p = &x[xbase + (size_t)lr * 128 + ks * 32 + grp * 8];
        f = pack8i(*reinterpret_cast<const float4*>(p),
                   *reinterpret_cast<const float4*>(p + 4));
      }
      xf[tt][ks] = f;
    }
  }

  // ---- V gemm (normal orientation): lane = d, regs = tokens ----
  f32x4 vacc[4][2];
  #pragma unroll
  for (int dt = 0; dt < 2; ++dt) {
    float bv = qkvb[256 + h * 32 + dt * 16 + l15];
    #pragma unroll
    for (int tt = 0; tt < 4; ++tt) vacc[tt][dt] = (f32x4){bv, bv, bv, bv};
  }
  #pragma unroll
  for (int ks = 0; ks < 4; ++ks) {
    short8 wv2[2];
    #pragma unroll
    for (int dt = 0; dt < 2; ++dt)
      wv2[dt] = *reinterpret_cast<const short8*>(
          &wbf[(size_t)(256 + h * 32 + dt * 16 + l15) * 128 + ks * 32 + grp * 8]);
    #pragma unroll
    for (int tt = 0; tt < 4; ++tt)
      #pragma unroll
      for (int dt = 0; dt < 2; ++dt)
        vacc[tt][dt] = __builtin_amdgcn_mfma_f32_16x16x32_bf16(xf[tt][ks], wv2[dt], vacc[tt][dt], 0, 0, 0);
  }
  // pack V for PV: k-slot order n = {2k2*16+grp*4+r, (2k2+1)*16+grp*4+r}
  short8 Vp[2][2];
  #pragma unroll
  for (int k2 = 0; k2 < 2; ++k2)
    #pragma unroll
    for (int dt = 0; dt < 2; ++dt)
      Vp[k2][dt] = pack8f(vacc[2 * k2][dt], vacc[2 * k2 + 1][dt]);

  // ---- Q,K gemm SWAPPED: qk[tt][nt] = mfma(w_frag, x_frag) ----
  // nt 0,1 = q dim-tiles; nt 2,3 = k dim-tiles. lane = token, reg = d.
  f32x4 qk[4][4];
  #pragma unroll
  for (int nt = 0; nt < 4; ++nt) {
    int base = (nt < 2 ? 0 : 128) + h * 32 + (nt & 1) * 16 + grp * 4;
    float4 b4 = *reinterpret_cast<const float4*>(&qkvb[base]);
    #pragma unroll
    for (int tt = 0; tt < 4; ++tt) qk[tt][nt] = (f32x4){b4.x, b4.y, b4.z, b4.w};
  }
  #pragma unroll
  for (int ks = 0; ks < 4; ++ks) {
    short8 wf[4];
    #pragma unroll
    for (int nt = 0; nt < 4; ++nt) {
      int brow = (nt < 2 ? 0 : 128) + h * 32 + (nt & 1) * 16 + l15;
      wf[nt] = *reinterpret_cast<const short8*>(&wbf[(size_t)brow * 128 + ks * 32 + grp * 8]);
    }
    #pragma unroll
    for (int tt = 0; tt < 4; ++tt)
      #pragma unroll
      for (int nt = 0; nt < 4; ++nt)
        qk[tt][nt] = __builtin_amdgcn_mfma_f32_16x16x32_bf16(wf[nt], xf[tt][ks], qk[tt][nt], 0, 0, 0);
  }
  // pack Q (scaled) and K with identical d-order {t*16+grp*4+r, 16+...}
  short8 Qp[4], Kp[4];
  #pragma unroll
  for (int tt = 0; tt < 4; ++tt) {
    Qp[tt] = pack8f(qk[tt][0] * SCALE_Q, qk[tt][1] * SCALE_Q);
    Kp[tt] = pack8f(qk[tt][2], qk[tt][3]);
  }

  // ---- per query-column-tile: S^T, softmax, PV, ao_lds write ----
  const f32x4 zero4 = (f32x4){0, 0, 0, 0};
  #pragma unroll
  for (int mt = 0; mt < 4; ++mt) {
    f32x4 s4[4];
    #pragma unroll
    for (int nt = 0; nt < 4; ++nt)
      s4[nt] = __builtin_amdgcn_mfma_f32_16x16x32_bf16(Kp[nt], Qp[mt], zero4, 0, 0, 0);

    const int m0 = mt * 16 + l15;
    const float* trow = &tab[(((size_t)(wdx * 4 + h)) * 64 + m0) * 64];
    f32x4 v[4];
    #pragma unroll
    for (int nt = 0; nt < 4; ++nt) {
      float4 tb = *reinterpret_cast<const float4*>(&trow[nt * 16 + grp * 4]);
      v[nt][0] = s4[nt][0] + tb.x;
      v[nt][1] = s4[nt][1] + tb.y;
      v[nt][2] = s4[nt][2] + tb.z;
      v[nt][3] = s4[nt][3] + tb.w;
    }
    float mx = v[0][0];
    #pragma unroll
    for (int nt = 0; nt < 4; ++nt)
      #pragma unroll
      for (int r = 0; r < 4; ++r) mx = fmaxf(mx, v[nt][r]);
    mx = fmaxf(mx, __shfl_xor(mx, 16));
    mx = fmaxf(mx, __shfl_xor(mx, 32));
    float sum = 0.f;
    f32x4 p4[4];
    #pragma unroll
    for (int nt = 0; nt < 4; ++nt)
      #pragma unroll
      for (int r = 0; r < 4; ++r) { p4[nt][r] = __expf(v[nt][r] - mx); sum += p4[nt][r]; }
    sum += __shfl_xor(sum, 16);
    sum += __shfl_xor(sum, 32);
    float ri = 1.0f / sum;
    #pragma unroll
    for (int nt = 0; nt < 4; ++nt) p4[nt] *= ri;

    short8 Pp0 = pack8f(p4[0], p4[1]);   // n-order matches Vp ✓
    short8 Pp1 = pack8f(p4[2], p4[3]);
    #pragma unroll
    for (int dt = 0; dt < 2; ++dt) {
      f32x4 ot = __builtin_amdgcn_mfma_f32_16x16x32_bf16(Vp[0][dt], Pp0, zero4, 0, 0, 0);
      ot = __builtin_amdgcn_mfma_f32_16x16x32_bf16(Vp[1][dt], Pp1, ot, 0, 0, 0);
      // O^T: lane col = token m0, rows = d = dt*16+grp*4+r -> 4 consecutive d
      *reinterpret_cast<int2*>(&ao_lds[m0][h * 32 + dt * 16 + grp * 4]) =
          pack4i(ot[0], ot[1], ot[2], ot[3]);
    }
  }
  __syncthreads();

  // ---- proj for own 16 token rows: out = ao @ pw^T + pb ----
  f32x4 pc[8];
  #pragma unroll
  for (int nt = 0; nt < 8; ++nt) {
    float bv = pb[nt * 16 + l15];
    pc[nt] = (f32x4){bv, bv, bv, bv};
  }
  #pragma unroll
  for (int ks = 0; ks < 4; ++ks) {
    short8 afr = *reinterpret_cast<const short8*>(&ao_lds[h * 16 + l15][ks * 32 + grp * 8]);
    #pragma unroll
    for (int nt = 0; nt < 8; ++nt) {
      short8 bfr = *reinterpret_cast<const short8*>(
          &pwbf[(size_t)(nt * 16 + l15) * 128 + ks * 32 + grp * 8]);
      pc[nt] = __builtin_amdgcn_mfma_f32_16x16x32_bf16(afr, bfr, pc[nt], 0, 0, 0);
    }
  }
  #pragma unroll
  for (int r = 0; r < 4; ++r) {
    int m = h * 16 + grp * 4 + r;
    if (m < 49) {
      float* orow = &out[xbase + (size_t)m * 128];
      #pragma unroll
      for (int nt = 0; nt < 8; ++nt)
        orow[nt * 16 + l15] = pc[nt][r];
    }
  }
}

// ---------------------------------------------------------------------------
extern "C" void kernel_launch(void* const* d_in, const int* in_sizes, int n_in,
                              void* d_out, int out_size, void* d_ws, size_t ws_size,
                              hipStream_t stream) {
  const float* x    = (const float*)d_in[0];
  const float* mask = (const float*)d_in[1];
  const float* qkvw = (const float*)d_in[2];
  const float* qkvb = (const float*)d_in[3];
  const float* rpb  = (const float*)d_in[4];
  const float* pw   = (const float*)d_in[5];
  const float* pb   = (const float*)d_in[6];
  float* out = (float*)d_out;

  char* ws = (char*)d_ws;
  short* wbf  = (short*)ws;                  // 384*128 bf16 = 98,304 B
  short* pwbf = (short*)(ws + 98304);        // 128*128 bf16 = 32,768 B
  float* tab  = (float*)(ws + 131072);       // 256*64*64 fp32 = 4,194,304 B

  k_prep <<<264,  256, 0, stream>>>(mask, rpb, qkvw, pw, tab, wbf, pwbf);
  k_fused<<<4096, 256, 0, stream>>>(x, qkvb, pb, tab, wbf, pwbf, out);
}

// Round 7
// 141.088 us; speedup vs baseline: 2.4146x; 1.3961x over previous
//
#include <hip/hip_runtime.h>
#include <hip/hip_bf16.h>

typedef __attribute__((ext_vector_type(8))) short short8;
typedef __attribute__((ext_vector_type(4))) short short4v;
typedef __attribute__((ext_vector_type(4))) float f32x4;

#define SCALE_Q 0.17677669529663687f

__device__ __forceinline__ short f2bf(float f) {
  union { float f; unsigned u; } v; v.f = f;
  unsigned r = (v.u + 0x7fffu + ((v.u >> 16) & 1u)) >> 16;
  return (short)r;
}

union S8U { short8 v; __hip_bfloat162 h[4]; int2 d[2]; };
union W4U { int2 d; __hip_bfloat162 h[2]; };

__device__ __forceinline__ short8 pack8i(float4 a, float4 b) {
  S8U r;
  r.h[0] = __float22bfloat162_rn(make_float2(a.x, a.y));
  r.h[1] = __float22bfloat162_rn(make_float2(a.z, a.w));
  r.h[2] = __float22bfloat162_rn(make_float2(b.x, b.y));
  r.h[3] = __float22bfloat162_rn(make_float2(b.z, b.w));
  return r.v;
}

__device__ __forceinline__ short8 pack8f(f32x4 a, f32x4 b) {
  S8U r;
  r.h[0] = __float22bfloat162_rn(make_float2(a[0], a[1]));
  r.h[1] = __float22bfloat162_rn(make_float2(a[2], a[3]));
  r.h[2] = __float22bfloat162_rn(make_float2(b[0], b[1]));
  r.h[3] = __float22bfloat162_rn(make_float2(b[2], b[3]));
  return r.v;
}

__device__ __forceinline__ int2 pack4i(float a, float b, float c, float d) {
  W4U w;
  w.h[0] = __float22bfloat162_rn(make_float2(a, b));
  w.h[1] = __float22bfloat162_rn(make_float2(c, d));
  return w.d;
}

// ---------------------------------------------------------------------------
// k_prep: fragment-major pre-swizzle so every k_fused operand load is
// `base + lane*16B` (fully coalesced, no L2 sector amplification).
//  wfsw[h][slot0..5(q0,q1,k0,k1,v0,v1)][ks][lane] : 8 bf16  (96 KB)
//  pwsw[nt0..7][ks][lane]                         : 8 bf16  (32 KB)
//  tabf[wdx][h][mt][nt][lane]                     : float4  (4 MB)
//    content(lane=grp*16+l15): rows l15-indexed, cols grp-indexed, exactly
//    the per-lane values the old gather loads produced.
// ---------------------------------------------------------------------------
__global__ __launch_bounds__(256) void k_prep(
    const float* __restrict__ mask, const float* __restrict__ rpb,
    const float* __restrict__ qkvw, const float* __restrict__ pw,
    float* __restrict__ tabf, short* __restrict__ wfsw, short* __restrict__ pwsw)
{
  const int bid = blockIdx.x, tid = threadIdx.x;
  if (bid < 256) {
    const int wdx = bid >> 2, hh = bid & 3;
    for (int i = 0; i < 4; ++i) {
      int e = tid + i * 256;                 // 0..1023 = [mt][nt][lane]
      int mt = e >> 8, nt = (e >> 6) & 3, ln = e & 63;
      int l = ln & 15, g = ln >> 4;
      int m = mt * 16 + l, n0 = nt * 16 + g * 4;
      float vv[4];
      #pragma unroll
      for (int j = 0; j < 4; ++j) {
        int n = n0 + j;
        float val;
        if (n >= 49)      val = -1e30f;
        else if (m >= 49) val = 0.0f;
        else {
          int mi = (m * 37) >> 8, mj = m - mi * 7;
          int ni = (n * 37) >> 8, nj = n - ni * 7;
          int ridx = (mi - ni + 6) * 13 + (mj - nj + 6);
          val = mask[(size_t)wdx * 2401 + m * 49 + n] + rpb[ridx * 4 + hh];
        }
        vv[j] = val;
      }
      float4* dst = reinterpret_cast<float4*>(&tabf[((size_t)bid * 1024 + e) * 4]);
      *dst = make_float4(vv[0], vv[1], vv[2], vv[3]);
    }
  } else {
    // weights: 6144 qkv entries + 2048 proj entries, 16 B each
    int e0 = (bid - 256) * 256 + tid;
    for (int i = 0; i < 4; ++i) {
      int e = e0 + i * 2048;                 // 0..8191
      const float* src;
      short* dst;
      if (e < 6144) {
        int hh = e / 1536, rem = e - hh * 1536;
        int slot = rem >> 8, ks = (rem >> 6) & 3, ln = rem & 63;
        int l = ln & 15, g = ln >> 4;
        int r = (slot >> 1) * 128 + hh * 32 + (slot & 1) * 16 + l;
        int c = ks * 32 + g * 8;
        src = &qkvw[(size_t)r * 128 + c];
        dst = wfsw + (size_t)e * 8;
      } else {
        int p = e - 6144;
        int nt = p >> 8, ks = (p >> 6) & 3, ln = p & 63;
        int l = ln & 15, g = ln >> 4;
        int r = nt * 16 + l, c = ks * 32 + g * 8;
        src = &pw[(size_t)r * 128 + c];
        dst = pwsw + (size_t)p * 8;
      }
      float4 a = *reinterpret_cast<const float4*>(src);
      float4 b = *reinterpret_cast<const float4*>(src + 4);
      *reinterpret_cast<short8*>(dst) = pack8i(a, b);
    }
  }
}

// ---------------------------------------------------------------------------
// k_fused: one WAVE per (window, head); block = window (4 waves).
// x staged once per block into LDS (coalesced), fragments read from LDS.
// All weight/table loads are lane-coalesced fragment arrays.
// Attention core all-register (swapped QK^T, 2-shuffle softmax, reg PV).
// ao exchanged through the dead x LDS buffer; proj per wave; fp32 out.
// ---------------------------------------------------------------------------
__global__ __launch_bounds__(256, 3) void k_fused(
    const float* __restrict__ x, const float* __restrict__ qkvb,
    const float* __restrict__ pb, const float* __restrict__ tabf,
    const short* __restrict__ wfsw, const short* __restrict__ pwsw,
    float* __restrict__ out)
{
  __shared__ short xs[64 * 136];        // x bf16 [64][136]; later ao overlay
  const int tid = threadIdx.x;
  const int lane = tid & 63;
  const int h = tid >> 6;               // wave id = head
  const int l15 = lane & 15, grp = lane >> 4;
  const int gwin = blockIdx.x;
  const int wdx = gwin & 63;
  const size_t xbase = (size_t)gwin * 49 * 128;

  // ---- zero pad rows 49..63, stage x (fp32 -> bf16, coalesced) ----
  for (int i = tid; i < 1020; i += 256)            // 15 rows * 68 ints
    reinterpret_cast<int*>(xs)[3332 + i] = 0;
  for (int i = tid; i < 1568; i += 256) {          // 49 rows * 32 float4
    int r = i >> 5, c4 = i & 31;
    float4 v = *reinterpret_cast<const float4*>(&x[xbase + (size_t)r * 128 + c4 * 4]);
    short4v s;
    s[0] = f2bf(v.x); s[1] = f2bf(v.y); s[2] = f2bf(v.z); s[3] = f2bf(v.w);
    *reinterpret_cast<short4v*>(&xs[r * 136 + c4 * 4]) = s;
  }
  __syncthreads();

  // ---- Q,K gemm SWAPPED: qk[tt][nt] = mfma(wf, xf); lane = token ----
  f32x4 qk[4][4];
  #pragma unroll
  for (int nt = 0; nt < 4; ++nt) {
    int base = (nt < 2 ? 0 : 128) + h * 32 + (nt & 1) * 16 + grp * 4;
    float4 b4 = *reinterpret_cast<const float4*>(&qkvb[base]);
    #pragma unroll
    for (int tt = 0; tt < 4; ++tt) qk[tt][nt] = (f32x4){b4.x, b4.y, b4.z, b4.w};
  }
  const short* wfh = wfsw + (size_t)h * 6 * 4 * 64 * 8;
  #pragma unroll
  for (int ks = 0; ks < 4; ++ks) {
    short8 wf[4];
    #pragma unroll
    for (int nt = 0; nt < 4; ++nt)
      wf[nt] = *reinterpret_cast<const short8*>(wfh + (((size_t)nt * 4 + ks) * 64 + lane) * 8);
    #pragma unroll
    for (int tt = 0; tt < 4; ++tt) {
      short8 xf = *reinterpret_cast<const short8*>(&xs[(tt * 16 + l15) * 136 + ks * 32 + grp * 8]);
      #pragma unroll
      for (int nt = 0; nt < 4; ++nt)
        qk[tt][nt] = __builtin_amdgcn_mfma_f32_16x16x32_bf16(wf[nt], xf, qk[tt][nt], 0, 0, 0);
    }
  }
  short8 Qp[4], Kp[4];
  #pragma unroll
  for (int tt = 0; tt < 4; ++tt) {
    Qp[tt] = pack8f(qk[tt][0] * SCALE_Q, qk[tt][1] * SCALE_Q);
    Kp[tt] = pack8f(qk[tt][2], qk[tt][3]);
  }

  // ---- V gemm (normal orientation): lane = d ----
  f32x4 vacc[4][2];
  #pragma unroll
  for (int dt = 0; dt < 2; ++dt) {
    float bv = qkvb[256 + h * 32 + dt * 16 + l15];
    #pragma unroll
    for (int tt = 0; tt < 4; ++tt) vacc[tt][dt] = (f32x4){bv, bv, bv, bv};
  }
  #pragma unroll
  for (int ks = 0; ks < 4; ++ks) {
    short8 wv[2];
    #pragma unroll
    for (int dt = 0; dt < 2; ++dt)
      wv[dt] = *reinterpret_cast<const short8*>(wfh + ((((size_t)4 + dt) * 4 + ks) * 64 + lane) * 8);
    #pragma unroll
    for (int tt = 0; tt < 4; ++tt) {
      short8 xf = *reinterpret_cast<const short8*>(&xs[(tt * 16 + l15) * 136 + ks * 32 + grp * 8]);
      #pragma unroll
      for (int dt = 0; dt < 2; ++dt)
        vacc[tt][dt] = __builtin_amdgcn_mfma_f32_16x16x32_bf16(xf, wv[dt], vacc[tt][dt], 0, 0, 0);
    }
  }
  short8 Vp[2][2];
  #pragma unroll
  for (int k2 = 0; k2 < 2; ++k2)
    #pragma unroll
    for (int dt = 0; dt < 2; ++dt)
      Vp[k2][dt] = pack8f(vacc[2 * k2][dt], vacc[2 * k2 + 1][dt]);

  __syncthreads();   // all xs reads done; ao overlay may begin

  // ---- per query-column-tile: S^T, softmax, PV -> ao overlay ----
  const f32x4 zero4 = (f32x4){0, 0, 0, 0};
  const float* tbase = tabf + (((size_t)(wdx * 4 + h)) * 16) * 256;  // [mt][nt][lane]*4
  #pragma unroll
  for (int mt = 0; mt < 4; ++mt) {
    f32x4 s4[4];
    #pragma unroll
    for (int nt = 0; nt < 4; ++nt)
      s4[nt] = __builtin_amdgcn_mfma_f32_16x16x32_bf16(Kp[nt], Qp[mt], zero4, 0, 0, 0);

    const int m0 = mt * 16 + l15;
    f32x4 v[4];
    #pragma unroll
    for (int nt = 0; nt < 4; ++nt) {
      float4 tb = *reinterpret_cast<const float4*>(tbase + (((size_t)mt * 4 + nt) * 64 + lane) * 4);
      v[nt][0] = s4[nt][0] + tb.x;
      v[nt][1] = s4[nt][1] + tb.y;
      v[nt][2] = s4[nt][2] + tb.z;
      v[nt][3] = s4[nt][3] + tb.w;
    }
    float mx = v[0][0];
    #pragma unroll
    for (int nt = 0; nt < 4; ++nt)
      #pragma unroll
      for (int r = 0; r < 4; ++r) mx = fmaxf(mx, v[nt][r]);
    mx = fmaxf(mx, __shfl_xor(mx, 16));
    mx = fmaxf(mx, __shfl_xor(mx, 32));
    float sum = 0.f;
    f32x4 p4[4];
    #pragma unroll
    for (int nt = 0; nt < 4; ++nt)
      #pragma unroll
      for (int r = 0; r < 4; ++r) { p4[nt][r] = __expf(v[nt][r] - mx); sum += p4[nt][r]; }
    sum += __shfl_xor(sum, 16);
    sum += __shfl_xor(sum, 32);
    float ri = 1.0f / sum;
    #pragma unroll
    for (int nt = 0; nt < 4; ++nt) p4[nt] *= ri;

    short8 Pp0 = pack8f(p4[0], p4[1]);
    short8 Pp1 = pack8f(p4[2], p4[3]);
    #pragma unroll
    for (int dt = 0; dt < 2; ++dt) {
      f32x4 ot = __builtin_amdgcn_mfma_f32_16x16x32_bf16(Vp[0][dt], Pp0, zero4, 0, 0, 0);
      ot = __builtin_amdgcn_mfma_f32_16x16x32_bf16(Vp[1][dt], Pp1, ot, 0, 0, 0);
      *reinterpret_cast<int2*>(&xs[m0 * 136 + h * 32 + dt * 16 + grp * 4]) =
          pack4i(ot[0], ot[1], ot[2], ot[3]);
    }
  }
  __syncthreads();   // ao complete

  // ---- proj for own 16 token rows: out = ao @ pw^T + pb ----
  f32x4 pc[8];
  #pragma unroll
  for (int nt = 0; nt < 8; ++nt) {
    float bv = pb[nt * 16 + l15];
    pc[nt] = (f32x4){bv, bv, bv, bv};
  }
  #pragma unroll
  for (int ks = 0; ks < 4; ++ks) {
    short8 afr = *reinterpret_cast<const short8*>(&xs[(h * 16 + l15) * 136 + ks * 32 + grp * 8]);
    #pragma unroll
    for (int nt = 0; nt < 8; ++nt) {
      short8 bfr = *reinterpret_cast<const short8*>(pwsw + (((size_t)nt * 4 + ks) * 64 + lane) * 8);
      pc[nt] = __builtin_amdgcn_mfma_f32_16x16x32_bf16(afr, bfr, pc[nt], 0, 0, 0);
    }
  }
  #pragma unroll
  for (int r = 0; r < 4; ++r) {
    int m = h * 16 + grp * 4 + r;
    if (m < 49) {
      float* orow = &out[xbase + (size_t)m * 128];
      #pragma unroll
      for (int nt = 0; nt < 8; ++nt)
        orow[nt * 16 + l15] = pc[nt][r];
    }
  }
}

// ---------------------------------------------------------------------------
extern "C" void kernel_launch(void* const* d_in, const int* in_sizes, int n_in,
                              void* d_out, int out_size, void* d_ws, size_t ws_size,
                              hipStream_t stream) {
  const float* x    = (const float*)d_in[0];
  const float* mask = (const float*)d_in[1];
  const float* qkvw = (const float*)d_in[2];
  const float* qkvb = (const float*)d_in[3];
  const float* rpb  = (const float*)d_in[4];
  const float* pw   = (const float*)d_in[5];
  const float* pb   = (const float*)d_in[6];
  float* out = (float*)d_out;

  char* ws = (char*)d_ws;
  short* wfsw = (short*)ws;                  // 4*6*4*64*16 B = 98,304 B
  short* pwsw = (short*)(ws + 98304);        // 8*4*64*16 B  = 32,768 B
  float* tabf = (float*)(ws + 131072);       // 256*16*64*16 B = 4,194,304 B

  k_prep <<<264,  256, 0, stream>>>(mask, rpb, qkvw, pw, tabf, wfsw, pwsw);
  k_fused<<<4096, 256, 0, stream>>>(x, qkvb, pb, tabf, wfsw, pwsw, out);
}

// Round 9
// 117.725 us; speedup vs baseline: 2.8938x; 1.1985x over previous
//
#include <hip/hip_runtime.h>
#include <hip/hip_bf16.h>

typedef __attribute__((ext_vector_type(8))) short short8;
typedef __attribute__((ext_vector_type(4))) short short4v;
typedef __attribute__((ext_vector_type(4))) float f32x4;

#define SCALE_QL 0.25504601521753316f   // (1/sqrt(32)) * log2(e)
#define LOG2E    1.4426950408889634f

__device__ __forceinline__ short f2bf(float f) {
  union { float f; unsigned u; } v; v.f = f;
  unsigned r = (v.u + 0x7fffu + ((v.u >> 16) & 1u)) >> 16;
  return (short)r;
}

union S8U { short8 v; __hip_bfloat162 h[4]; int2 d[2]; };
union W4U { int2 d; __hip_bfloat162 h[2]; };

__device__ __forceinline__ short8 pack8i(float4 a, float4 b) {
  S8U r;
  r.h[0] = __float22bfloat162_rn(make_float2(a.x, a.y));
  r.h[1] = __float22bfloat162_rn(make_float2(a.z, a.w));
  r.h[2] = __float22bfloat162_rn(make_float2(b.x, b.y));
  r.h[3] = __float22bfloat162_rn(make_float2(b.z, b.w));
  return r.v;
}

__device__ __forceinline__ short8 pack8f(f32x4 a, f32x4 b) {
  S8U r;
  r.h[0] = __float22bfloat162_rn(make_float2(a[0], a[1]));
  r.h[1] = __float22bfloat162_rn(make_float2(a[2], a[3]));
  r.h[2] = __float22bfloat162_rn(make_float2(b[0], b[1]));
  r.h[3] = __float22bfloat162_rn(make_float2(b[2], b[3]));
  return r.v;
}

__device__ __forceinline__ int2 pack4i(float a, float b, float c, float d) {
  W4U w;
  w.h[0] = __float22bfloat162_rn(make_float2(a, b));
  w.h[1] = __float22bfloat162_rn(make_float2(c, d));
  return w.d;
}

// ---------------------------------------------------------------------------
// k_prep: fragment-major pre-swizzle (identical layout to round 7) with the
// bias table pre-multiplied by log2(e) for native exp2 softmax.
// ---------------------------------------------------------------------------
__global__ __launch_bounds__(256) void k_prep(
    const float* __restrict__ mask, const float* __restrict__ rpb,
    const float* __restrict__ qkvw, const float* __restrict__ pw,
    float* __restrict__ tabf, short* __restrict__ wfsw, short* __restrict__ pwsw)
{
  const int bid = blockIdx.x, tid = threadIdx.x;
  if (bid < 256) {
    const int wdx = bid >> 2, hh = bid & 3;
    for (int i = 0; i < 4; ++i) {
      int e = tid + i * 256;                 // [mt][nt][lane]
      int mt = e >> 8, nt = (e >> 6) & 3, ln = e & 63;
      int l = ln & 15, g = ln >> 4;
      int m = mt * 16 + l, n0 = nt * 16 + g * 4;
      float vv[4];
      #pragma unroll
      for (int j = 0; j < 4; ++j) {
        int n = n0 + j;
        float val;
        if (n >= 49)      val = -1e30f;
        else if (m >= 49) val = 0.0f;
        else {
          int mi = (m * 37) >> 8, mj = m - mi * 7;
          int ni = (n * 37) >> 8, nj = n - ni * 7;
          int ridx = (mi - ni + 6) * 13 + (mj - nj + 6);
          val = mask[(size_t)wdx * 2401 + m * 49 + n] + rpb[ridx * 4 + hh];
        }
        vv[j] = val * LOG2E;
      }
      float4* dst = reinterpret_cast<float4*>(&tabf[((size_t)bid * 1024 + e) * 4]);
      *dst = make_float4(vv[0], vv[1], vv[2], vv[3]);
    }
  } else {
    int e0 = (bid - 256) * 256 + tid;
    for (int i = 0; i < 4; ++i) {
      int e = e0 + i * 2048;
      const float* src;
      short* dst;
      if (e < 6144) {
        int hh = e / 1536, rem = e - hh * 1536;
        int slot = rem >> 8, ks = (rem >> 6) & 3, ln = rem & 63;
        int l = ln & 15, g = ln >> 4;
        int r = (slot >> 1) * 128 + hh * 32 + (slot & 1) * 16 + l;
        int c = ks * 32 + g * 8;
        src = &qkvw[(size_t)r * 128 + c];
        dst = wfsw + (size_t)e * 8;
      } else {
        int p = e - 6144;
        int nt = p >> 8, ks = (p >> 6) & 3, ln = p & 63;
        int l = ln & 15, g = ln >> 4;
        int r = nt * 16 + l, c = ks * 32 + g * 8;
        src = &pw[(size_t)r * 128 + c];
        dst = pwsw + (size_t)p * 8;
      }
      float4 a = *reinterpret_cast<const float4*>(src);
      float4 b = *reinterpret_cast<const float4*>(src + 4);
      *reinterpret_cast<short8*>(dst) = pack8i(a, b);
    }
  }
}

// ---------------------------------------------------------------------------
// k_fused: block = 4 waves (one per head) processing 4 windows with
// double-buffered x LDS + explicit prefetch pipelines on every operand
// stream (defeats the round-7 serial-load stall).
// ---------------------------------------------------------------------------
__global__ __launch_bounds__(256) void k_fused(
    const float* __restrict__ x, const float* __restrict__ qkvb,
    const float* __restrict__ pb, const float* __restrict__ tabf,
    const short* __restrict__ wfsw, const short* __restrict__ pwsw,
    float* __restrict__ out)
{
  __shared__ short xs[2][64 * 136];
  const int tid = threadIdx.x;
  const int lane = tid & 63;
  const int h = tid >> 6;
  const int l15 = lane & 15, grp = lane >> 4;
  const int win0 = blockIdx.x * 4;
  const short* wfh = wfsw + (size_t)h * 6 * 4 * 64 * 8;
  const f32x4 zero4 = (f32x4){0, 0, 0, 0};

  // ---- prologue: stage window win0 into xs[0] ----
  {
    const size_t xb = (size_t)win0 * 49 * 128;
    #pragma unroll
    for (int i = 0; i < 7; ++i) {
      int idx = tid + i * 256;
      if (idx < 1568) {
        int r = idx >> 5, c4 = idx & 31;
        float4 v = *reinterpret_cast<const float4*>(&x[xb + (size_t)r * 128 + c4 * 4]);
        short4v s; s[0] = f2bf(v.x); s[1] = f2bf(v.y); s[2] = f2bf(v.z); s[3] = f2bf(v.w);
        *reinterpret_cast<short4v*>(&xs[0][r * 136 + c4 * 4]) = s;
      }
    }
    #pragma unroll
    for (int i = 0; i < 4; ++i) {
      int idx = tid + i * 256;
      if (idx < 960) {               // zero rows 49..63, cols 0..127
        int r = 49 + (idx >> 6), c = idx & 63;
        *reinterpret_cast<int*>(&xs[0][r * 136 + c * 2]) = 0;
      }
    }
  }
  __syncthreads();

  for (int w = 0; w < 4; ++w) {
    const int gwin = win0 + w;
    const int wdx = gwin & 63;
    short* cs = xs[w & 1];
    short* ns = xs[(w & 1) ^ 1];
    const size_t obase = (size_t)gwin * 49 * 128;

    // ---- QK gemm (swapped): qk[tt][nt] = mfma(wf, xf); wf ping-pong ----
    f32x4 qk[4][4];
    #pragma unroll
    for (int nt = 0; nt < 4; ++nt) {
      int base = (nt < 2 ? 0 : 128) + h * 32 + (nt & 1) * 16 + grp * 4;
      float4 b4 = *reinterpret_cast<const float4*>(&qkvb[base]);
      #pragma unroll
      for (int tt = 0; tt < 4; ++tt) qk[tt][nt] = (f32x4){b4.x, b4.y, b4.z, b4.w};
    }
    short8 wfc[4], wfn[4];
    #pragma unroll
    for (int nt = 0; nt < 4; ++nt)
      wfc[nt] = *reinterpret_cast<const short8*>(wfh + (((size_t)nt * 4 + 0) * 64 + lane) * 8);
    #pragma unroll
    for (int ks = 0; ks < 4; ++ks) {
      if (ks < 3) {
        #pragma unroll
        for (int nt = 0; nt < 4; ++nt)
          wfn[nt] = *reinterpret_cast<const short8*>(wfh + (((size_t)nt * 4 + ks + 1) * 64 + lane) * 8);
        __builtin_amdgcn_sched_barrier(0);
      }
      #pragma unroll
      for (int tt = 0; tt < 4; ++tt) {
        short8 xf = *reinterpret_cast<const short8*>(&cs[(tt * 16 + l15) * 136 + ks * 32 + grp * 8]);
        #pragma unroll
        for (int nt = 0; nt < 4; ++nt)
          qk[tt][nt] = __builtin_amdgcn_mfma_f32_16x16x32_bf16(wfc[nt], xf, qk[tt][nt], 0, 0, 0);
      }
      #pragma unroll
      for (int nt = 0; nt < 4; ++nt) wfc[nt] = wfn[nt];
    }
    short8 Qp[4], Kp[4];
    #pragma unroll
    for (int tt = 0; tt < 4; ++tt) {
      Qp[tt] = pack8f(qk[tt][0] * SCALE_QL, qk[tt][1] * SCALE_QL);  // log2e folded
      Kp[tt] = pack8f(qk[tt][2], qk[tt][3]);
    }

    // ---- issue x loads for window w+1 (latency hidden under V gemm etc) ----
    float4 xr[7];
    if (w < 3) {
      const size_t xb2 = (size_t)(gwin + 1) * 49 * 128;
      #pragma unroll
      for (int i = 0; i < 7; ++i) {
        int idx = tid + i * 256;
        if (idx < 1568)
          xr[i] = *reinterpret_cast<const float4*>(&x[xb2 + (size_t)(idx >> 5) * 128 + (idx & 31) * 4]);
      }
      __builtin_amdgcn_sched_barrier(0);
    }

    // ---- V gemm (normal orientation), wv ping-pong ----
    f32x4 vacc[4][2];
    #pragma unroll
    for (int dt = 0; dt < 2; ++dt) {
      float bv = qkvb[256 + h * 32 + dt * 16 + l15];
      #pragma unroll
      for (int tt = 0; tt < 4; ++tt) vacc[tt][dt] = (f32x4){bv, bv, bv, bv};
    }
    short8 wvc[2], wvn[2];
    #pragma unroll
    for (int dt = 0; dt < 2; ++dt)
      wvc[dt] = *reinterpret_cast<const short8*>(wfh + ((((size_t)4 + dt) * 4 + 0) * 64 + lane) * 8);
    #pragma unroll
    for (int ks = 0; ks < 4; ++ks) {
      if (ks < 3) {
        #pragma unroll
        for (int dt = 0; dt < 2; ++dt)
          wvn[dt] = *reinterpret_cast<const short8*>(wfh + ((((size_t)4 + dt) * 4 + ks + 1) * 64 + lane) * 8);
        __builtin_amdgcn_sched_barrier(0);
      }
      #pragma unroll
      for (int tt = 0; tt < 4; ++tt) {
        short8 xf = *reinterpret_cast<const short8*>(&cs[(tt * 16 + l15) * 136 + ks * 32 + grp * 8]);
        #pragma unroll
        for (int dt = 0; dt < 2; ++dt)
          vacc[tt][dt] = __builtin_amdgcn_mfma_f32_16x16x32_bf16(xf, wvc[dt], vacc[tt][dt], 0, 0, 0);
      }
      #pragma unroll
      for (int dt = 0; dt < 2; ++dt) wvc[dt] = wvn[dt];
    }
    short8 Vp[2][2];
    #pragma unroll
    for (int k2 = 0; k2 < 2; ++k2)
      #pragma unroll
      for (int dt = 0; dt < 2; ++dt)
        Vp[k2][dt] = pack8f(vacc[2 * k2][dt], vacc[2 * k2 + 1][dt]);

    // ---- write x[w+1] into ns (+ zero pad rows) ----
    if (w < 3) {
      #pragma unroll
      for (int i = 0; i < 7; ++i) {
        int idx = tid + i * 256;
        if (idx < 1568) {
          short4v s;
          s[0] = f2bf(xr[i].x); s[1] = f2bf(xr[i].y); s[2] = f2bf(xr[i].z); s[3] = f2bf(xr[i].w);
          *reinterpret_cast<short4v*>(&ns[(idx >> 5) * 136 + (idx & 31) * 4]) = s;
        }
      }
      #pragma unroll
      for (int i = 0; i < 4; ++i) {
        int idx = tid + i * 256;
        if (idx < 960) {
          int r = 49 + (idx >> 6), c = idx & 63;
          *reinterpret_cast<int*>(&ns[r * 136 + c * 2]) = 0;
        }
      }
    }

    // ---- prefetch bias-table for mt=0, then barrier ----
    const float* tbase = tabf + (((size_t)(wdx * 4 + h)) * 16) * 256;
    float4 tbc[4], tbn[4];
    #pragma unroll
    for (int nt = 0; nt < 4; ++nt)
      tbc[nt] = *reinterpret_cast<const float4*>(tbase + (((size_t)nt) * 64 + lane) * 4);
    __syncthreads();   // B1: cs reads done -> ao overlay allowed

    // ---- per query-column-tile: S^T, exp2 softmax, PV -> ao overlay ----
    #pragma unroll
    for (int mt = 0; mt < 4; ++mt) {
      if (mt < 3) {
        #pragma unroll
        for (int nt = 0; nt < 4; ++nt)
          tbn[nt] = *reinterpret_cast<const float4*>(tbase + (((size_t)(mt + 1) * 4 + nt) * 64 + lane) * 4);
        __builtin_amdgcn_sched_barrier(0);
      }
      f32x4 s4[4];
      #pragma unroll
      for (int nt = 0; nt < 4; ++nt)
        s4[nt] = __builtin_amdgcn_mfma_f32_16x16x32_bf16(Kp[nt], Qp[mt], zero4, 0, 0, 0);
      const int m0 = mt * 16 + l15;
      f32x4 v[4];
      #pragma unroll
      for (int nt = 0; nt < 4; ++nt) {
        v[nt][0] = s4[nt][0] + tbc[nt].x;
        v[nt][1] = s4[nt][1] + tbc[nt].y;
        v[nt][2] = s4[nt][2] + tbc[nt].z;
        v[nt][3] = s4[nt][3] + tbc[nt].w;
      }
      float mx = v[0][0];
      #pragma unroll
      for (int nt = 0; nt < 4; ++nt)
        #pragma unroll
        for (int r = 0; r < 4; ++r) mx = fmaxf(mx, v[nt][r]);
      mx = fmaxf(mx, __shfl_xor(mx, 16));
      mx = fmaxf(mx, __shfl_xor(mx, 32));
      float sum = 0.f;
      f32x4 p4[4];
      #pragma unroll
      for (int nt = 0; nt < 4; ++nt)
        #pragma unroll
        for (int r = 0; r < 4; ++r) {
          p4[nt][r] = __builtin_amdgcn_exp2f(v[nt][r] - mx);
          sum += p4[nt][r];
        }
      sum += __shfl_xor(sum, 16);
      sum += __shfl_xor(sum, 32);
      float ri = 1.0f / sum;
      #pragma unroll
      for (int nt = 0; nt < 4; ++nt) p4[nt] *= ri;

      short8 Pp0 = pack8f(p4[0], p4[1]);
      short8 Pp1 = pack8f(p4[2], p4[3]);
      #pragma unroll
      for (int dt = 0; dt < 2; ++dt) {
        f32x4 ot = __builtin_amdgcn_mfma_f32_16x16x32_bf16(Vp[0][dt], Pp0, zero4, 0, 0, 0);
        ot = __builtin_amdgcn_mfma_f32_16x16x32_bf16(Vp[1][dt], Pp1, ot, 0, 0, 0);
        *reinterpret_cast<int2*>(&cs[m0 * 136 + h * 32 + dt * 16 + grp * 4]) =
            pack4i(ot[0], ot[1], ot[2], ot[3]);
      }
      #pragma unroll
      for (int nt = 0; nt < 4; ++nt) tbc[nt] = tbn[nt];
    }
    __syncthreads();   // B2: ao complete -> proj reads

    // ---- proj for own 16 token rows, pw ping-pong (8-wide batches) ----
    f32x4 pc[8];
    #pragma unroll
    for (int nt = 0; nt < 8; ++nt) {
      float bv = pb[nt * 16 + l15];
      pc[nt] = (f32x4){bv, bv, bv, bv};
    }
    short8 bc[8], bn[8];
    #pragma unroll
    for (int nt = 0; nt < 8; ++nt)
      bc[nt] = *reinterpret_cast<const short8*>(pwsw + (((size_t)nt * 4 + 0) * 64 + lane) * 8);
    #pragma unroll
    for (int ks = 0; ks < 4; ++ks) {
      if (ks < 3) {
        #pragma unroll
        for (int nt = 0; nt < 8; ++nt)
          bn[nt] = *reinterpret_cast<const short8*>(pwsw + (((size_t)nt * 4 + ks + 1) * 64 + lane) * 8);
        __builtin_amdgcn_sched_barrier(0);
      }
      short8 afr = *reinterpret_cast<const short8*>(&cs[(h * 16 + l15) * 136 + ks * 32 + grp * 8]);
      #pragma unroll
      for (int nt = 0; nt < 8; ++nt)
        pc[nt] = __builtin_amdgcn_mfma_f32_16x16x32_bf16(afr, bc[nt], pc[nt], 0, 0, 0);
      #pragma unroll
      for (int nt = 0; nt < 8; ++nt) bc[nt] = bn[nt];
    }
    #pragma unroll
    for (int r = 0; r < 4; ++r) {
      int m = h * 16 + grp * 4 + r;
      if (m < 49) {
        float* orow = &out[obase + (size_t)m * 128];
        #pragma unroll
        for (int nt = 0; nt < 8; ++nt)
          orow[nt * 16 + l15] = pc[nt][r];
      }
    }
    __syncthreads();   // B3: proj reads done -> buffer reuse next window
  }
}

// ---------------------------------------------------------------------------
extern "C" void kernel_launch(void* const* d_in, const int* in_sizes, int n_in,
                              void* d_out, int out_size, void* d_ws, size_t ws_size,
                              hipStream_t stream) {
  const float* x    = (const float*)d_in[0];
  const float* mask = (const float*)d_in[1];
  const float* qkvw = (const float*)d_in[2];
  const float* qkvb = (const float*)d_in[3];
  const float* rpb  = (const float*)d_in[4];
  const float* pw   = (const float*)d_in[5];
  const float* pb   = (const float*)d_in[6];
  float* out = (float*)d_out;

  char* ws = (char*)d_ws;
  short* wfsw = (short*)ws;                  // 4*6*4*64*16 B = 98,304 B
  short* pwsw = (short*)(ws + 98304);        // 8*4*64*16 B  = 32,768 B
  float* tabf = (float*)(ws + 131072);       // 256*16*64*16 B = 4,194,304 B

  k_prep <<<264,  256, 0, stream>>>(mask, rpb, qkvw, pw, tabf, wfsw, pwsw);
  k_fused<<<1024, 256, 0, stream>>>(x, qkvb, pb, tabf, wfsw, pwsw, out);
}

// Round 10
// 80.121 us; speedup vs baseline: 4.2520x; 1.4693x over previous
//
#include <hip/hip_runtime.h>
#include <hip/hip_bf16.h>

typedef __attribute__((ext_vector_type(8))) short short8;
typedef __attribute__((ext_vector_type(4))) short short4v;
typedef __attribute__((ext_vector_type(4))) float f32x4;

#define SCALE_QL 0.25504601521753316f   // (1/sqrt(32)) * log2(e)
#define LOG2E    1.4426950408889634f

__device__ __forceinline__ short f2bf(float f) {
  union { float f; unsigned u; } v; v.f = f;
  unsigned r = (v.u + 0x7fffu + ((v.u >> 16) & 1u)) >> 16;
  return (short)r;
}

union S8U { short8 v; __hip_bfloat162 h[4]; int2 d[2]; };
union W4U { int2 d; __hip_bfloat162 h[2]; };

__device__ __forceinline__ short8 pack8i(float4 a, float4 b) {
  S8U r;
  r.h[0] = __float22bfloat162_rn(make_float2(a.x, a.y));
  r.h[1] = __float22bfloat162_rn(make_float2(a.z, a.w));
  r.h[2] = __float22bfloat162_rn(make_float2(b.x, b.y));
  r.h[3] = __float22bfloat162_rn(make_float2(b.z, b.w));
  return r.v;
}

__device__ __forceinline__ short8 pack8f(f32x4 a, f32x4 b) {
  S8U r;
  r.h[0] = __float22bfloat162_rn(make_float2(a[0], a[1]));
  r.h[1] = __float22bfloat162_rn(make_float2(a[2], a[3]));
  r.h[2] = __float22bfloat162_rn(make_float2(b[0], b[1]));
  r.h[3] = __float22bfloat162_rn(make_float2(b[2], b[3]));
  return r.v;
}

__device__ __forceinline__ int2 pack4i(float a, float b, float c, float d) {
  W4U w;
  w.h[0] = __float22bfloat162_rn(make_float2(a, b));
  w.h[1] = __float22bfloat162_rn(make_float2(c, d));
  return w.d;
}

// ---------------------------------------------------------------------------
// k_prep: fragment-major pre-swizzle; bias table pre-multiplied by log2(e).
// ---------------------------------------------------------------------------
__global__ __launch_bounds__(256) void k_prep(
    const float* __restrict__ mask, const float* __restrict__ rpb,
    const float* __restrict__ qkvw, const float* __restrict__ pw,
    float* __restrict__ tabf, short* __restrict__ wfsw, short* __restrict__ pwsw)
{
  const int bid = blockIdx.x, tid = threadIdx.x;
  if (bid < 256) {
    const int wdx = bid >> 2, hh = bid & 3;
    for (int i = 0; i < 4; ++i) {
      int e = tid + i * 256;                 // [mt][nt][lane]
      int mt = e >> 8, nt = (e >> 6) & 3, ln = e & 63;
      int l = ln & 15, g = ln >> 4;
      int m = mt * 16 + l, n0 = nt * 16 + g * 4;
      float vv[4];
      #pragma unroll
      for (int j = 0; j < 4; ++j) {
        int n = n0 + j;
        float val;
        if (n >= 49)      val = -1e30f;
        else if (m >= 49) val = 0.0f;
        else {
          int mi = (m * 37) >> 8, mj = m - mi * 7;
          int ni = (n * 37) >> 8, nj = n - ni * 7;
          int ridx = (mi - ni + 6) * 13 + (mj - nj + 6);
          val = mask[(size_t)wdx * 2401 + m * 49 + n] + rpb[ridx * 4 + hh];
        }
        vv[j] = val * LOG2E;
      }
      float4* dst = reinterpret_cast<float4*>(&tabf[((size_t)bid * 1024 + e) * 4]);
      *dst = make_float4(vv[0], vv[1], vv[2], vv[3]);
    }
  } else {
    int e0 = (bid - 256) * 256 + tid;
    for (int i = 0; i < 4; ++i) {
      int e = e0 + i * 2048;
      const float* src;
      short* dst;
      if (e < 6144) {
        int hh = e / 1536, rem = e - hh * 1536;
        int slot = rem >> 8, ks = (rem >> 6) & 3, ln = rem & 63;
        int l = ln & 15, g = ln >> 4;
        int r = (slot >> 1) * 128 + hh * 32 + (slot & 1) * 16 + l;
        int c = ks * 32 + g * 8;
        src = &qkvw[(size_t)r * 128 + c];
        dst = wfsw + (size_t)e * 8;
      } else {
        int p = e - 6144;
        int nt = p >> 8, ks = (p >> 6) & 3, ln = p & 63;
        int l = ln & 15, g = ln >> 4;
        int r = nt * 16 + l, c = ks * 32 + g * 8;
        src = &pw[(size_t)r * 128 + c];
        dst = pwsw + (size_t)p * 8;
      }
      float4 a = *reinterpret_cast<const float4*>(src);
      float4 b = *reinterpret_cast<const float4*>(src + 4);
      *reinterpret_cast<short8*>(dst) = pack8i(a, b);
    }
  }
}

// ---------------------------------------------------------------------------
// k_fused: one window per block, 4 waves (one per head). Round-9 pipelined
// loads kept; window-batching/double-buffer dropped and proj loop inverted
// to cut the live register set (256 -> ~160) for 3x the occupancy.
// ---------------------------------------------------------------------------
__global__ __launch_bounds__(256, 3) void k_fused(
    const float* __restrict__ x, const float* __restrict__ qkvb,
    const float* __restrict__ pb, const float* __restrict__ tabf,
    const short* __restrict__ wfsw, const short* __restrict__ pwsw,
    float* __restrict__ out)
{
  __shared__ short xs[64 * 136];       // x bf16 [64][136]; later ao overlay
  const int tid = threadIdx.x;
  const int lane = tid & 63;
  const int h = tid >> 6;
  const int l15 = lane & 15, grp = lane >> 4;
  const int gwin = blockIdx.x;
  const int wdx = gwin & 63;
  const size_t xbase = (size_t)gwin * 49 * 128;
  const short* wfh = wfsw + (size_t)h * 6 * 4 * 64 * 8;
  const f32x4 zero4 = (f32x4){0, 0, 0, 0};

  // ---- stage x (fp32 -> bf16, coalesced) + zero pad rows 49..63 ----
  #pragma unroll
  for (int i = 0; i < 7; ++i) {
    int idx = tid + i * 256;
    if (idx < 1568) {
      int r = idx >> 5, c4 = idx & 31;
      float4 v = *reinterpret_cast<const float4*>(&x[xbase + (size_t)r * 128 + c4 * 4]);
      short4v s; s[0] = f2bf(v.x); s[1] = f2bf(v.y); s[2] = f2bf(v.z); s[3] = f2bf(v.w);
      *reinterpret_cast<short4v*>(&xs[r * 136 + c4 * 4]) = s;
    }
  }
  #pragma unroll
  for (int i = 0; i < 4; ++i) {
    int idx = tid + i * 256;
    if (idx < 960) {
      int r = 49 + (idx >> 6), c = idx & 63;
      *reinterpret_cast<int*>(&xs[r * 136 + c * 2]) = 0;
    }
  }
  __syncthreads();

  // ---- QK gemm (swapped): qk[tt][nt] = mfma(wf, xf); wf ping-pong ----
  f32x4 qk[4][4];
  #pragma unroll
  for (int nt = 0; nt < 4; ++nt) {
    int base = (nt < 2 ? 0 : 128) + h * 32 + (nt & 1) * 16 + grp * 4;
    float4 b4 = *reinterpret_cast<const float4*>(&qkvb[base]);
    #pragma unroll
    for (int tt = 0; tt < 4; ++tt) qk[tt][nt] = (f32x4){b4.x, b4.y, b4.z, b4.w};
  }
  {
    short8 wfc[4], wfn[4];
    #pragma unroll
    for (int nt = 0; nt < 4; ++nt)
      wfc[nt] = *reinterpret_cast<const short8*>(wfh + (((size_t)nt * 4 + 0) * 64 + lane) * 8);
    #pragma unroll
    for (int ks = 0; ks < 4; ++ks) {
      if (ks < 3) {
        #pragma unroll
        for (int nt = 0; nt < 4; ++nt)
          wfn[nt] = *reinterpret_cast<const short8*>(wfh + (((size_t)nt * 4 + ks + 1) * 64 + lane) * 8);
        __builtin_amdgcn_sched_barrier(0);
      }
      #pragma unroll
      for (int tt = 0; tt < 4; ++tt) {
        short8 xf = *reinterpret_cast<const short8*>(&xs[(tt * 16 + l15) * 136 + ks * 32 + grp * 8]);
        #pragma unroll
        for (int nt = 0; nt < 4; ++nt)
          qk[tt][nt] = __builtin_amdgcn_mfma_f32_16x16x32_bf16(wfc[nt], xf, qk[tt][nt], 0, 0, 0);
      }
      #pragma unroll
      for (int nt = 0; nt < 4; ++nt) wfc[nt] = wfn[nt];
    }
  }
  short8 Qp[4], Kp[4];
  #pragma unroll
  for (int tt = 0; tt < 4; ++tt) {
    Qp[tt] = pack8f(qk[tt][0] * SCALE_QL, qk[tt][1] * SCALE_QL);  // log2e folded
    Kp[tt] = pack8f(qk[tt][2], qk[tt][3]);
  }

  // ---- V gemm (normal orientation), wv ping-pong ----
  short8 Vp[2][2];
  {
    f32x4 vacc[4][2];
    #pragma unroll
    for (int dt = 0; dt < 2; ++dt) {
      float bv = qkvb[256 + h * 32 + dt * 16 + l15];
      #pragma unroll
      for (int tt = 0; tt < 4; ++tt) vacc[tt][dt] = (f32x4){bv, bv, bv, bv};
    }
    short8 wvc[2], wvn[2];
    #pragma unroll
    for (int dt = 0; dt < 2; ++dt)
      wvc[dt] = *reinterpret_cast<const short8*>(wfh + ((((size_t)4 + dt) * 4 + 0) * 64 + lane) * 8);
    #pragma unroll
    for (int ks = 0; ks < 4; ++ks) {
      if (ks < 3) {
        #pragma unroll
        for (int dt = 0; dt < 2; ++dt)
          wvn[dt] = *reinterpret_cast<const short8*>(wfh + ((((size_t)4 + dt) * 4 + ks + 1) * 64 + lane) * 8);
        __builtin_amdgcn_sched_barrier(0);
      }
      #pragma unroll
      for (int tt = 0; tt < 4; ++tt) {
        short8 xf = *reinterpret_cast<const short8*>(&xs[(tt * 16 + l15) * 136 + ks * 32 + grp * 8]);
        #pragma unroll
        for (int dt = 0; dt < 2; ++dt)
          vacc[tt][dt] = __builtin_amdgcn_mfma_f32_16x16x32_bf16(xf, wvc[dt], vacc[tt][dt], 0, 0, 0);
      }
      #pragma unroll
      for (int dt = 0; dt < 2; ++dt) wvc[dt] = wvn[dt];
    }
    #pragma unroll
    for (int k2 = 0; k2 < 2; ++k2)
      #pragma unroll
      for (int dt = 0; dt < 2; ++dt)
        Vp[k2][dt] = pack8f(vacc[2 * k2][dt], vacc[2 * k2 + 1][dt]);
  }

  // ---- prefetch bias-table for mt=0, then barrier (xs reads all done) ----
  const float* tbase = tabf + (((size_t)(wdx * 4 + h)) * 16) * 256;
  float4 tbc[4], tbn[4];
  #pragma unroll
  for (int nt = 0; nt < 4; ++nt)
    tbc[nt] = *reinterpret_cast<const float4*>(tbase + (((size_t)nt) * 64 + lane) * 4);
  __syncthreads();   // B1: ao overlay allowed

  // ---- per query-column-tile: S^T, exp2 softmax, PV -> ao overlay ----
  #pragma unroll
  for (int mt = 0; mt < 4; ++mt) {
    if (mt < 3) {
      #pragma unroll
      for (int nt = 0; nt < 4; ++nt)
        tbn[nt] = *reinterpret_cast<const float4*>(tbase + (((size_t)(mt + 1) * 4 + nt) * 64 + lane) * 4);
      __builtin_amdgcn_sched_barrier(0);
    }
    f32x4 s4[4];
    #pragma unroll
    for (int nt = 0; nt < 4; ++nt)
      s4[nt] = __builtin_amdgcn_mfma_f32_16x16x32_bf16(Kp[nt], Qp[mt], zero4, 0, 0, 0);
    const int m0 = mt * 16 + l15;
    #pragma unroll
    for (int nt = 0; nt < 4; ++nt) {
      s4[nt][0] += tbc[nt].x;
      s4[nt][1] += tbc[nt].y;
      s4[nt][2] += tbc[nt].z;
      s4[nt][3] += tbc[nt].w;
    }
    float mx = s4[0][0];
    #pragma unroll
    for (int nt = 0; nt < 4; ++nt)
      #pragma unroll
      for (int r = 0; r < 4; ++r) mx = fmaxf(mx, s4[nt][r]);
    mx = fmaxf(mx, __shfl_xor(mx, 16));
    mx = fmaxf(mx, __shfl_xor(mx, 32));
    float sum = 0.f;
    #pragma unroll
    for (int nt = 0; nt < 4; ++nt)
      #pragma unroll
      for (int r = 0; r < 4; ++r) {
        s4[nt][r] = __builtin_amdgcn_exp2f(s4[nt][r] - mx);
        sum += s4[nt][r];
      }
    sum += __shfl_xor(sum, 16);
    sum += __shfl_xor(sum, 32);
    float ri = 1.0f / sum;
    #pragma unroll
    for (int nt = 0; nt < 4; ++nt) s4[nt] *= ri;

    short8 Pp0 = pack8f(s4[0], s4[1]);
    short8 Pp1 = pack8f(s4[2], s4[3]);
    #pragma unroll
    for (int dt = 0; dt < 2; ++dt) {
      f32x4 ot = __builtin_amdgcn_mfma_f32_16x16x32_bf16(Vp[0][dt], Pp0, zero4, 0, 0, 0);
      ot = __builtin_amdgcn_mfma_f32_16x16x32_bf16(Vp[1][dt], Pp1, ot, 0, 0, 0);
      *reinterpret_cast<int2*>(&xs[m0 * 136 + h * 32 + dt * 16 + grp * 4]) =
          pack4i(ot[0], ot[1], ot[2], ot[3]);
    }
    #pragma unroll
    for (int nt = 0; nt < 4; ++nt) tbc[nt] = tbn[nt];
  }
  __syncthreads();   // B2: ao complete -> proj reads

  // ---- proj for own 16 token rows; nt-outer loop (pc = one f32x4) ----
  short8 afr[4];
  #pragma unroll
  for (int ks = 0; ks < 4; ++ks)
    afr[ks] = *reinterpret_cast<const short8*>(&xs[(h * 16 + l15) * 136 + ks * 32 + grp * 8]);
  short8 bc[4], bn[4];
  #pragma unroll
  for (int ks = 0; ks < 4; ++ks)
    bc[ks] = *reinterpret_cast<const short8*>(pwsw + (((size_t)0 * 4 + ks) * 64 + lane) * 8);
  #pragma unroll
  for (int nt = 0; nt < 8; ++nt) {
    if (nt < 7) {
      #pragma unroll
      for (int ks = 0; ks < 4; ++ks)
        bn[ks] = *reinterpret_cast<const short8*>(pwsw + (((size_t)(nt + 1) * 4 + ks) * 64 + lane) * 8);
      __builtin_amdgcn_sched_barrier(0);
    }
    float bv = pb[nt * 16 + l15];
    f32x4 pc = (f32x4){bv, bv, bv, bv};
    #pragma unroll
    for (int ks = 0; ks < 4; ++ks)
      pc = __builtin_amdgcn_mfma_f32_16x16x32_bf16(afr[ks], bc[ks], pc, 0, 0, 0);
    #pragma unroll
    for (int r = 0; r < 4; ++r) {
      int m = h * 16 + grp * 4 + r;
      if (m < 49)
        out[xbase + (size_t)m * 128 + nt * 16 + l15] = pc[r];
    }
    #pragma unroll
    for (int ks = 0; ks < 4; ++ks) bc[ks] = bn[ks];
  }
}

// ---------------------------------------------------------------------------
extern "C" void kernel_launch(void* const* d_in, const int* in_sizes, int n_in,
                              void* d_out, int out_size, void* d_ws, size_t ws_size,
                              hipStream_t stream) {
  const float* x    = (const float*)d_in[0];
  const float* mask = (const float*)d_in[1];
  const float* qkvw = (const float*)d_in[2];
  const float* qkvb = (const float*)d_in[3];
  const float* rpb  = (const float*)d_in[4];
  const float* pw   = (const float*)d_in[5];
  const float* pb   = (const float*)d_in[6];
  float* out = (float*)d_out;

  char* ws = (char*)d_ws;
  short* wfsw = (short*)ws;                  // 4*6*4*64*16 B = 98,304 B
  short* pwsw = (short*)(ws + 98304);        // 8*4*64*16 B  = 32,768 B
  float* tabf = (float*)(ws + 131072);       // 256*16*64*16 B = 4,194,304 B

  k_prep <<<264,  256, 0, stream>>>(mask, rpb, qkvw, pw, tabf, wfsw, pwsw);
  k_fused<<<4096, 256, 0, stream>>>(x, qkvb, pb, tabf, wfsw, pwsw, out);
}